// Round 1
// baseline (772.854 us; speedup 1.0000x reference)
//
#include <hip/hip_runtime.h>
#include <hip/hip_bf16.h>
#include <math.h>

// Problem constants
#define TT 243
#define JJ 17
#define ICC 32
#define CC 544            // J*IC
#define BSS 3
#define NBB 81            // T/BS
#define KK 6
#define HH 8
#define HD 68             // C/H
#define DEPTH 2
#define HID 1088          // 2*C
#define BB 512
#define MTOK 3072         // B*K tokens
#define EPSF 1e-6f

// ---------------------------------------------------------------------------
// Kernel 1: x.reshape(B,T,C)+pos -> shift first half by 1 timestep -> 3-block
// mean -> xb (B,81,544); also y0[b,n] = mean_c xb
// ---------------------------------------------------------------------------
__global__ __launch_bounds__(576) void stage_a_kernel(
    const float* __restrict__ x,    // B*T*C
    const float* __restrict__ pos,  // T*C
    float* __restrict__ xb,         // B*81*C
    float* __restrict__ y0)         // B*81
{
    const int n = blockIdx.x;   // 0..80
    const int b = blockIdx.y;   // 0..511
    const int c = threadIdx.x;  // 0..575

    float v = 0.0f;
    if (c < CC) {
        const int tbase = n * 3 + ((c < (CC / 2)) ? -1 : 0);
        const float* xr = x + (size_t)b * TT * CC;
        float s = 0.0f;
#pragma unroll
        for (int i = 0; i < 3; ++i) {
            const int tt = tbase + i;
            if (tt >= 0) s += xr[(size_t)tt * CC + c] + pos[tt * CC + c];
        }
        v = s * (1.0f / 3.0f);
        xb[((size_t)b * NBB + n) * CC + c] = v;
    }
    // block reduction of v over the 544 active threads (9 waves)
    float a = v;
#pragma unroll
    for (int off = 32; off; off >>= 1) a += __shfl_down(a, off);
    __shared__ float sa[9];
    const int wid = threadIdx.x >> 6;
    const int lane = threadIdx.x & 63;
    if (lane == 0) sa[wid] = a;
    __syncthreads();
    if (threadIdx.x == 0) {
        float s = 0.0f;
#pragma unroll
        for (int w = 0; w < 9; ++w) s += sa[w];
        y0[(size_t)b * NBB + n] = s / (float)CC;
    }
}

// ---------------------------------------------------------------------------
// Kernel 2: per-b MLP (81x81 twice) + sigmoid + top-6 + gather t0 = xb[idx]
// ---------------------------------------------------------------------------
__global__ __launch_bounds__(128) void select_kernel(
    const float* __restrict__ y0,    // B*81
    const float* __restrict__ fc1,   // 81*81
    const float* __restrict__ fc2,   // 81*81
    const float* __restrict__ xb,    // B*81*C
    float* __restrict__ t0)          // B*6*C
{
    const int b = blockIdx.x;
    const int tid = threadIdx.x;
    __shared__ float sy[NBB], sz[NBB], sw[NBB];
    __shared__ int sidx[KK];

    if (tid < NBB) sy[tid] = y0[(size_t)b * NBB + tid];
    __syncthreads();
    if (tid < NBB) {
        float s = 0.0f;
        for (int j = 0; j < NBB; ++j) s += fc1[tid * NBB + j] * sy[j];
        sz[tid] = fmaxf(s, 0.0f);
    }
    __syncthreads();
    if (tid < NBB) {
        float s = 0.0f;
        for (int j = 0; j < NBB; ++j) s += fc2[tid * NBB + j] * sz[j];
        sw[tid] = 1.0f / (1.0f + expf(-s));
    }
    __syncthreads();
    if (tid == 0) {
        unsigned long long used0 = 0ull, used1 = 0ull;
        for (int kk = 0; kk < KK; ++kk) {
            float best = -1e30f;
            int bi = 0;
            for (int j = 0; j < NBB; ++j) {
                const bool u = (j < 64) ? ((used0 >> j) & 1ull) : ((used1 >> (j - 64)) & 1ull);
                if (!u && sw[j] > best) { best = sw[j]; bi = j; }
            }
            sidx[kk] = bi;
            if (bi < 64) used0 |= (1ull << bi); else used1 |= (1ull << (bi - 64));
        }
    }
    __syncthreads();
    for (int i = tid; i < KK * CC; i += 128) {
        const int kk = i / CC;
        const int c = i - kk * CC;
        t0[(size_t)b * KK * CC + i] = xb[((size_t)b * NBB + sidx[kk]) * CC + c];
    }
}

// ---------------------------------------------------------------------------
// LayerNorm over last dim (544) of an (M,544) matrix
// ---------------------------------------------------------------------------
__global__ __launch_bounds__(256) void ln_kernel(
    const float* __restrict__ X,   // M x 544
    const float* __restrict__ g,   // 544
    const float* __restrict__ bta, // 544
    float* __restrict__ Y)         // M x 544
{
    const int row = blockIdx.x;
    const float* xr = X + (size_t)row * CC;
    const int tid = threadIdx.x;
    float vals[3];
    float s = 0.0f, s2 = 0.0f;
#pragma unroll
    for (int i = 0; i < 3; ++i) {
        const int c = tid + i * 256;
        const float v = (c < CC) ? xr[c] : 0.0f;
        vals[i] = v;
        s += v;
        s2 += v * v;
    }
#pragma unroll
    for (int off = 32; off; off >>= 1) {
        s += __shfl_down(s, off);
        s2 += __shfl_down(s2, off);
    }
    __shared__ float sa[4], sb[4];
    __shared__ float mean_s, inv_s;
    const int wid = tid >> 6, lane = tid & 63;
    if (lane == 0) { sa[wid] = s; sb[wid] = s2; }
    __syncthreads();
    if (tid == 0) {
        const float S = sa[0] + sa[1] + sa[2] + sa[3];
        const float S2 = sb[0] + sb[1] + sb[2] + sb[3];
        const float m = S / (float)CC;
        const float var = S2 / (float)CC - m * m;
        mean_s = m;
        inv_s = rsqrtf(var + EPSF);
    }
    __syncthreads();
    const float m = mean_s, inv = inv_s;
    float* yr = Y + (size_t)row * CC;
#pragma unroll
    for (int i = 0; i < 3; ++i) {
        const int c = tid + i * 256;
        if (c < CC) yr[c] = (vals[i] - m) * inv * g[c] + bta[c];
    }
}

// ---------------------------------------------------------------------------
// Tiled f32 GEMM: Y[M,N] = act(X[M,K] @ W[N,K]^T + bias[N]) (+ residual R)
// 64x64 tile, 4x4 per thread, BK=16.  M % 64 == 0, K % 16 == 0, N guarded.
// ACT: 0 = none, 1 = exact gelu
// ---------------------------------------------------------------------------
template <int ACT, bool RES>
__global__ __launch_bounds__(256) void gemm_bt_kernel(
    const float* __restrict__ X,
    const float* __restrict__ W,
    const float* __restrict__ bias,
    const float* __restrict__ R,
    float* __restrict__ Y,
    int M, int N, int Kd)
{
    const int bm = blockIdx.y * 64;
    const int bn = blockIdx.x * 64;
    __shared__ float As[16][68];
    __shared__ float Bs[16][68];
    const int tid = threadIdx.x;
    const int tx = tid & 15;        // n-dir
    const int ty = tid >> 4;        // m-dir
    const int lr = tid >> 2;        // 0..63 row for loads
    const int lk = (tid & 3) * 4;   // k offset for float4 loads

    float acc[4][4] = {};

    for (int k0 = 0; k0 < Kd; k0 += 16) {
        const float4 a = *(const float4*)&X[(size_t)(bm + lr) * Kd + k0 + lk];
        float4 bv4;
        const int wr = bn + lr;
        if (wr < N) bv4 = *(const float4*)&W[(size_t)wr * Kd + k0 + lk];
        else        bv4 = make_float4(0.f, 0.f, 0.f, 0.f);
        __syncthreads();   // protect previous iteration's reads
        As[lk + 0][lr] = a.x; As[lk + 1][lr] = a.y; As[lk + 2][lr] = a.z; As[lk + 3][lr] = a.w;
        Bs[lk + 0][lr] = bv4.x; Bs[lk + 1][lr] = bv4.y; Bs[lk + 2][lr] = bv4.z; Bs[lk + 3][lr] = bv4.w;
        __syncthreads();
#pragma unroll
        for (int kk = 0; kk < 16; ++kk) {
            const float4 av = *(const float4*)&As[kk][ty * 4];
            const float4 bv = *(const float4*)&Bs[kk][tx * 4];
            const float aa[4] = {av.x, av.y, av.z, av.w};
            const float bb[4] = {bv.x, bv.y, bv.z, bv.w};
#pragma unroll
            for (int i2 = 0; i2 < 4; ++i2)
#pragma unroll
                for (int j2 = 0; j2 < 4; ++j2)
                    acc[i2][j2] += aa[i2] * bb[j2];
        }
    }

#pragma unroll
    for (int i2 = 0; i2 < 4; ++i2) {
        const int row = bm + ty * 4 + i2;
#pragma unroll
        for (int j2 = 0; j2 < 4; ++j2) {
            const int col = bn + tx * 4 + j2;
            if (col < N) {
                float v = acc[i2][j2] + bias[col];
                if (ACT == 1) v = 0.5f * v * (1.0f + erff(v * 0.70710678118654752f));
                if (RES) v += R[(size_t)row * N + col];
                Y[(size_t)row * N + col] = v;
            }
        }
    }
}

// ---------------------------------------------------------------------------
// Attention: per block b; 8 waves = 8 heads; K=6 tokens, head dim 68
// qkv rows (per token): [q(8x68) | k(8x68) | v(8x68)]  (1632 floats)
// ---------------------------------------------------------------------------
__global__ __launch_bounds__(512) void attn_kernel(
    const float* __restrict__ qkv,  // B*6*1632
    float* __restrict__ o)          // B*6*544
{
    const int b = blockIdx.x;
    __shared__ float sq[KK * 3 * CC];   // 6*1632 floats
    __shared__ float sp[HH][40];        // 36 scores per head (padded)
    const int tid = threadIdx.x;

    const float* src = qkv + (size_t)b * KK * 3 * CC;
    for (int i = tid; i < KK * 3 * CC; i += 512) sq[i] = src[i];
    __syncthreads();

    const int h = tid >> 6;
    const int lane = tid & 63;
    const float scl = rsqrtf((float)HD);

    if (lane < KK * KK) {
        const int n = lane / KK, m = lane - (lane / KK) * KK;
        const float* qp = &sq[n * (3 * CC) + 0 * CC + h * HD];
        const float* kp = &sq[m * (3 * CC) + 1 * CC + h * HD];
        float s = 0.0f;
#pragma unroll 4
        for (int d = 0; d < HD; ++d) s += qp[d] * kp[d];
        sp[h][lane] = s * scl;
    }
    __syncthreads();
    if (lane < KK) {
        const int n = lane;
        float mx = -1e30f;
#pragma unroll
        for (int m = 0; m < KK; ++m) mx = fmaxf(mx, sp[h][n * KK + m]);
        float e[KK];
        float sum = 0.0f;
#pragma unroll
        for (int m = 0; m < KK; ++m) { e[m] = expf(sp[h][n * KK + m] - mx); sum += e[m]; }
        const float inv = 1.0f / sum;
#pragma unroll
        for (int m = 0; m < KK; ++m) sp[h][n * KK + m] = e[m] * inv;
    }
    __syncthreads();
    for (int i = tid; i < KK * CC; i += 512) {
        const int n = i / CC;
        const int cd = i - n * CC;
        const int hh = cd / HD;
        const int d = cd - hh * HD;
        float acc = 0.0f;
#pragma unroll
        for (int m = 0; m < KK; ++m)
            acc += sp[hh][n * KK + m] * sq[m * (3 * CC) + 2 * CC + hh * HD + d];
        o[(size_t)b * KK * CC + i] = acc;
    }
}

// ---------------------------------------------------------------------------
// Final: out[b,c] = sum_k tln[b,k,c]*wm2_w[k] + wm2_b
// ---------------------------------------------------------------------------
__global__ __launch_bounds__(256) void out_kernel(
    const float* __restrict__ tln,   // B*6*544 (already LN'd)
    const float* __restrict__ wm2w,  // 6
    const float* __restrict__ wm2b,  // 1
    float* __restrict__ out)         // B*544
{
    const int i = blockIdx.x * 256 + threadIdx.x;
    if (i >= BB * CC) return;
    const int b = i / CC;
    const int c = i - b * CC;
    float acc = 0.0f;
#pragma unroll
    for (int k = 0; k < KK; ++k)
        acc += tln[((size_t)b * KK + k) * CC + c] * wm2w[k];
    out[i] = acc + wm2b[0];
}

// ---------------------------------------------------------------------------
extern "C" void kernel_launch(void* const* d_in, const int* in_sizes, int n_in,
                              void* d_out, int out_size, void* d_ws, size_t ws_size,
                              hipStream_t stream)
{
    const float* x      = (const float*)d_in[0];
    const float* pos    = (const float*)d_in[1];
    const float* fc1_w  = (const float*)d_in[2];
    const float* fc2_w  = (const float*)d_in[3];
    const float* ln1_g  = (const float*)d_in[4];
    const float* ln1_b  = (const float*)d_in[5];
    const float* qkv_w  = (const float*)d_in[6];
    const float* qkv_b  = (const float*)d_in[7];
    const float* proj_w = (const float*)d_in[8];
    const float* proj_b = (const float*)d_in[9];
    const float* ln2_g  = (const float*)d_in[10];
    const float* ln2_b  = (const float*)d_in[11];
    const float* mfc1_w = (const float*)d_in[12];
    const float* mfc1_b = (const float*)d_in[13];
    const float* mfc2_w = (const float*)d_in[14];
    const float* mfc2_b = (const float*)d_in[15];
    const float* lnf_g  = (const float*)d_in[16];
    const float* lnf_b  = (const float*)d_in[17];
    const float* wm2_w  = (const float*)d_in[18];
    const float* wm2_b  = (const float*)d_in[19];

    float* ws = (float*)d_ws;
    float* xb   = ws;                      // 512*81*544 = 22,560,768
    float* y0   = xb + (size_t)BB * NBB * CC;          // 41,472
    float* t    = y0 + (size_t)BB * NBB;               // 3072*544
    float* h    = t + (size_t)MTOK * CC;               // 3072*544
    float* qkvb = h + (size_t)MTOK * CC;               // 3072*1632 (reused as g)
    float* ob   = qkvb + (size_t)MTOK * 3 * CC;        // 3072*544

    // Stage A: pos-embed + shift + block mean (+ per-block channel mean)
    stage_a_kernel<<<dim3(NBB, BB), 576, 0, stream>>>(x, pos, xb, y0);

    // Selection MLP + top-6 + gather
    select_kernel<<<BB, 128, 0, stream>>>(y0, fc1_w, fc2_w, xb, t);

    for (int i = 0; i < DEPTH; ++i) {
        ln_kernel<<<MTOK, 256, 0, stream>>>(t, ln1_g + i * CC, ln1_b + i * CC, h);
        gemm_bt_kernel<0, false><<<dim3(26, 48), 256, 0, stream>>>(
            h, qkv_w + (size_t)i * 3 * CC * CC, qkv_b + (size_t)i * 3 * CC,
            nullptr, qkvb, MTOK, 3 * CC, CC);
        attn_kernel<<<BB, 512, 0, stream>>>(qkvb, ob);
        gemm_bt_kernel<0, true><<<dim3(9, 48), 256, 0, stream>>>(
            ob, proj_w + (size_t)i * CC * CC, proj_b + (size_t)i * CC,
            t, t, MTOK, CC, CC);
        ln_kernel<<<MTOK, 256, 0, stream>>>(t, ln2_g + i * CC, ln2_b + i * CC, h);
        gemm_bt_kernel<1, false><<<dim3(17, 48), 256, 0, stream>>>(
            h, mfc1_w + (size_t)i * HID * CC, mfc1_b + (size_t)i * HID,
            nullptr, qkvb /* g */, MTOK, HID, CC);
        gemm_bt_kernel<0, true><<<dim3(9, 48), 256, 0, stream>>>(
            qkvb, mfc2_w + (size_t)i * CC * HID, mfc2_b + (size_t)i * CC,
            t, t, MTOK, CC, HID);
    }

    // Final LN + weighted sum over K
    ln_kernel<<<MTOK, 256, 0, stream>>>(t, lnf_g, lnf_b, h);
    out_kernel<<<(BB * CC + 255) / 256, 256, 0, stream>>>(h, wm2_w, wm2_b, (float*)d_out);
}

// Round 2
// 322.938 us; speedup vs baseline: 2.3932x; 2.3932x over previous
//
#include <hip/hip_runtime.h>
#include <hip/hip_bf16.h>
#include <math.h>

// Problem constants
#define TT 243
#define CC 544            // J*IC
#define NBB 81            // T/BS
#define KK 6
#define HH 8
#define HD 68             // C/H
#define DEPTH 2
#define HID 1088          // 2*C
#define BB 512
#define MTOK 3072         // B*K tokens
#define EPSF 1e-6f

typedef __attribute__((ext_vector_type(8))) short bf16x8;
typedef __attribute__((ext_vector_type(4))) float f32x4;

__device__ __forceinline__ __hip_bfloat16 f2b(float f) { return __float2bfloat16(f); }

// ---------------------------------------------------------------------------
// Weight conversion f32 -> bf16 (concatenated: qkv | proj | mfc1 | mfc2)
// float4-index space segment ends:
#define E0 443904      // qkv  (2*1632*544/4)
#define E1 591872      // proj (+2*544*544/4)
#define E2 887808      // mfc1 (+2*1088*544/4)
#define E3 1183744     // mfc2 (+2*544*1088/4)
__global__ __launch_bounds__(256) void wconv_kernel(
    const float* __restrict__ s0, const float* __restrict__ s1,
    const float* __restrict__ s2, const float* __restrict__ s3,
    __hip_bfloat16* __restrict__ dst)
{
    const int i = blockIdx.x * 256 + threadIdx.x;
    if (i >= E3) return;
    float4 v;
    if (i < E0)      v = ((const float4*)s0)[i];
    else if (i < E1) v = ((const float4*)s1)[i - E0];
    else if (i < E2) v = ((const float4*)s2)[i - E1];
    else             v = ((const float4*)s3)[i - E2];
    ushort4 o;
    __hip_bfloat16 h;
    h = f2b(v.x); o.x = *(unsigned short*)&h;
    h = f2b(v.y); o.y = *(unsigned short*)&h;
    h = f2b(v.z); o.z = *(unsigned short*)&h;
    h = f2b(v.w); o.w = *(unsigned short*)&h;
    ((ushort4*)dst)[i] = o;
}

// ---------------------------------------------------------------------------
// Row half-sums: L[b,t] = sum_{c<272}(x+pos), R[b,t] = sum_{c>=272}(x+pos)
// wave per row, float4 loads
// ---------------------------------------------------------------------------
__global__ __launch_bounds__(256) void rowsum_kernel(
    const float* __restrict__ x,    // B*T*C
    const float* __restrict__ pos,  // T*C
    float* __restrict__ L,          // B*T
    float* __restrict__ R)          // B*T
{
    const int r = blockIdx.x * 4 + (threadIdx.x >> 6);   // 0..124415
    const int lane = threadIdx.x & 63;
    const int tt = r % TT;
    const float4* xr = (const float4*)x + (size_t)r * 136;
    const float4* pr = (const float4*)pos + (size_t)tt * 136;
    float sL = 0.0f, sR = 0.0f;
#pragma unroll
    for (int it = 0; it < 3; ++it) {
        const int c4 = lane + it * 64;
        if (c4 < 136) {
            const float4 xv = xr[c4];
            const float4 pv = pr[c4];
            const float s = (xv.x + pv.x) + (xv.y + pv.y) + (xv.z + pv.z) + (xv.w + pv.w);
            if (c4 < 68) sL += s; else sR += s;
        }
    }
#pragma unroll
    for (int off = 32; off; off >>= 1) {
        sL += __shfl_down(sL, off);
        sR += __shfl_down(sR, off);
    }
    if (lane == 0) { L[r] = sL; R[r] = sR; }
}

// ---------------------------------------------------------------------------
// Selection: y0 from L/R, 81x81 MLP x2, sigmoid, top-6, gather t from x+pos
// ---------------------------------------------------------------------------
__global__ __launch_bounds__(128) void select_kernel(
    const float* __restrict__ L,     // B*T
    const float* __restrict__ R,     // B*T
    const float* __restrict__ fc1,   // 81*81
    const float* __restrict__ fc2,   // 81*81
    const float* __restrict__ x,     // B*T*C
    const float* __restrict__ pos,   // T*C
    float* __restrict__ t0)          // B*6*C (f32)
{
    const int b = blockIdx.x;
    const int tid = threadIdx.x;
    __shared__ float sy[NBB], sz[NBB], sw[NBB];
    __shared__ int sidx[KK];

    if (tid < NBB) {
        const int n = tid;
        const float* Lb = L + (size_t)b * TT;
        const float* Rb = R + (size_t)b * TT;
        float s = Lb[3 * n] + Lb[3 * n + 1] + Rb[3 * n] + Rb[3 * n + 1] + Rb[3 * n + 2];
        if (n > 0) s += Lb[3 * n - 1];
        sy[n] = s * (1.0f / (3.0f * (float)CC));
    }
    __syncthreads();
    if (tid < NBB) {
        float s = 0.0f;
        for (int j = 0; j < NBB; ++j) s += fc1[tid * NBB + j] * sy[j];
        sz[tid] = fmaxf(s, 0.0f);
    }
    __syncthreads();
    if (tid < NBB) {
        float s = 0.0f;
        for (int j = 0; j < NBB; ++j) s += fc2[tid * NBB + j] * sz[j];
        sw[tid] = 1.0f / (1.0f + expf(-s));
    }
    __syncthreads();
    if (tid == 0) {
        unsigned long long used0 = 0ull, used1 = 0ull;
        for (int kk = 0; kk < KK; ++kk) {
            float best = -1e30f;
            int bi = 0;
            for (int j = 0; j < NBB; ++j) {
                const bool u = (j < 64) ? ((used0 >> j) & 1ull) : ((used1 >> (j - 64)) & 1ull);
                if (!u && sw[j] > best) { best = sw[j]; bi = j; }
            }
            sidx[kk] = bi;
            if (bi < 64) used0 |= (1ull << bi); else used1 |= (1ull << (bi - 64));
        }
    }
    __syncthreads();
    // gather: t0[b,k,c] = mean over 3 rows of shifted (x+pos)
    const float4* x4 = (const float4*)x;
    const float4* p4 = (const float4*)pos;
    float4* t4 = (float4*)t0;
    for (int i = tid; i < KK * 136; i += 128) {
        const int k = i / 136;
        const int c4 = i - k * 136;
        const int n = sidx[k];
        const int shift = (c4 < 68) ? -1 : 0;
        float ax = 0.f, ay = 0.f, az = 0.f, aw = 0.f;
#pragma unroll
        for (int i2 = 0; i2 < 3; ++i2) {
            const int ttr = 3 * n + i2 + shift;
            if (ttr >= 0) {
                const float4 xv = x4[((size_t)b * TT + ttr) * 136 + c4];
                const float4 pv = p4[(size_t)ttr * 136 + c4];
                ax += xv.x + pv.x; ay += xv.y + pv.y; az += xv.z + pv.z; aw += xv.w + pv.w;
            }
        }
        const float inv3 = 1.0f / 3.0f;
        t4[((size_t)b * KK + k) * 136 + c4] = make_float4(ax * inv3, ay * inv3, az * inv3, aw * inv3);
    }
}

// ---------------------------------------------------------------------------
// LayerNorm over last dim (544), output bf16
// ---------------------------------------------------------------------------
__global__ __launch_bounds__(256) void ln_bf16_kernel(
    const float* __restrict__ X,   // M x 544
    const float* __restrict__ g,   // 544
    const float* __restrict__ bta, // 544
    __hip_bfloat16* __restrict__ Y)
{
    const int row = blockIdx.x;
    const float* xr = X + (size_t)row * CC;
    const int tid = threadIdx.x;
    float vals[3];
    float s = 0.0f, s2 = 0.0f;
#pragma unroll
    for (int i = 0; i < 3; ++i) {
        const int c = tid + i * 256;
        const float v = (c < CC) ? xr[c] : 0.0f;
        vals[i] = v;
        s += v;
        s2 += v * v;
    }
#pragma unroll
    for (int off = 32; off; off >>= 1) {
        s += __shfl_down(s, off);
        s2 += __shfl_down(s2, off);
    }
    __shared__ float sa[4], sb[4];
    __shared__ float mean_s, inv_s;
    const int wid = tid >> 6, lane = tid & 63;
    if (lane == 0) { sa[wid] = s; sb[wid] = s2; }
    __syncthreads();
    if (tid == 0) {
        const float S = sa[0] + sa[1] + sa[2] + sa[3];
        const float S2 = sb[0] + sb[1] + sb[2] + sb[3];
        const float m = S / (float)CC;
        const float var = S2 / (float)CC - m * m;
        mean_s = m;
        inv_s = rsqrtf(var + EPSF);
    }
    __syncthreads();
    const float m = mean_s, inv = inv_s;
    __hip_bfloat16* yr = Y + (size_t)row * CC;
#pragma unroll
    for (int i = 0; i < 3; ++i) {
        const int c = tid + i * 256;
        if (c < CC) yr[c] = f2b((vals[i] - m) * inv * g[c] + bta[c]);
    }
}

// ---------------------------------------------------------------------------
// bf16 MFMA GEMM: Y[M,N] = act(Xbf[M,K] @ Wbf[N,K]^T + bias[N]) (+R) (f32/bf16 out)
// 128x128 tile, BK=32, 256 threads = 4 waves (2x2), wave tile 64x64
// ---------------------------------------------------------------------------
template <int ACT, int RES, int OBF>
__global__ __launch_bounds__(256) void gemm_mfma_kernel(
    const unsigned short* __restrict__ X,   // bf16 M x K
    const unsigned short* __restrict__ W,   // bf16 N x K
    const float* __restrict__ bias,         // N
    const float* __restrict__ R,            // M x N (f32) or null
    void* __restrict__ Y,                   // f32 or bf16
    int M, int N, int Kd)
{
    const int bm = blockIdx.y * 128;
    const int bn = blockIdx.x * 128;
    const int tid = threadIdx.x;
    const int K8 = Kd >> 3;    // uint4 per row

    __shared__ __align__(16) short As[128][40];
    __shared__ __align__(16) short Bs[128][40];

    // staging map: 2 chunks each for A and B; chunk = 16B = 8 bf16
    const int r0 = tid >> 2;           // rows 0..63
    const int c0 = tid & 3;            // chunk 0..3
    const int r1 = r0 + 64;            // rows 64..127

    const uint4* Xu = (const uint4*)X;
    const uint4* Wu = (const uint4*)W;

    const int wid = tid >> 6;
    const int lane = tid & 63;
    const int wm = (wid >> 1) * 64;
    const int wn = (wid & 1) * 64;
    const int l16 = lane & 15;
    const int l4 = lane >> 4;          // 0..3
    const int koff = l4 * 8;

    f32x4 acc[4][4] = {};

    const int wr0 = min(bn + r0, N - 1);
    const int wr1 = min(bn + r1, N - 1);

    uint4 a0 = Xu[(size_t)(bm + r0) * K8 + c0];
    uint4 a1 = Xu[(size_t)(bm + r1) * K8 + c0];
    uint4 b0 = Wu[(size_t)wr0 * K8 + c0];
    uint4 b1 = Wu[(size_t)wr1 * K8 + c0];

    const int nk = Kd >> 5;
    for (int kt = 0; kt < nk; ++kt) {
        __syncthreads();
        *(uint4*)&As[r0][c0 * 8] = a0;
        *(uint4*)&As[r1][c0 * 8] = a1;
        *(uint4*)&Bs[r0][c0 * 8] = b0;
        *(uint4*)&Bs[r1][c0 * 8] = b1;
        __syncthreads();

        const bool more = (kt + 1 < nk);
        uint4 na0, na1, nb0, nb1;
        if (more) {
            const int kc = (kt + 1) * 4 + c0;
            na0 = Xu[(size_t)(bm + r0) * K8 + kc];
            na1 = Xu[(size_t)(bm + r1) * K8 + kc];
            nb0 = Wu[(size_t)wr0 * K8 + kc];
            nb1 = Wu[(size_t)wr1 * K8 + kc];
        }

        bf16x8 af[4], bf[4];
#pragma unroll
        for (int mf = 0; mf < 4; ++mf) af[mf] = *(const bf16x8*)&As[wm + mf * 16 + l16][koff];
#pragma unroll
        for (int nf = 0; nf < 4; ++nf) bf[nf] = *(const bf16x8*)&Bs[wn + nf * 16 + l16][koff];
#pragma unroll
        for (int mf = 0; mf < 4; ++mf)
#pragma unroll
            for (int nf = 0; nf < 4; ++nf)
                acc[mf][nf] = __builtin_amdgcn_mfma_f32_16x16x32_bf16(af[mf], bf[nf], acc[mf][nf], 0, 0, 0);

        if (more) { a0 = na0; a1 = na1; b0 = nb0; b1 = nb1; }
    }

    // epilogue
#pragma unroll
    for (int nf = 0; nf < 4; ++nf) {
        const int col = bn + wn + nf * 16 + l16;
        if (col < N) {
            const float bs = bias[col];
#pragma unroll
            for (int mf = 0; mf < 4; ++mf) {
#pragma unroll
                for (int j = 0; j < 4; ++j) {
                    const int row = bm + wm + mf * 16 + l4 * 4 + j;
                    float v = acc[mf][nf][j] + bs;
                    if (ACT == 1) v = 0.5f * v * (1.0f + erff(v * 0.70710678118654752f));
                    if (RES) v += R[(size_t)row * N + col];
                    if (OBF) ((__hip_bfloat16*)Y)[(size_t)row * N + col] = f2b(v);
                    else     ((float*)Y)[(size_t)row * N + col] = v;
                }
            }
        }
    }
}

// ---------------------------------------------------------------------------
// Attention: per block b; 8 waves = 8 heads; 6 tokens, head dim 68; out bf16
// ---------------------------------------------------------------------------
__global__ __launch_bounds__(512) void attn_kernel(
    const float* __restrict__ qkv,       // B*6*1632 f32
    __hip_bfloat16* __restrict__ o)      // B*6*544 bf16
{
    const int b = blockIdx.x;
    __shared__ float sq[KK * 3 * CC];
    __shared__ float sp[HH][40];
    const int tid = threadIdx.x;

    const float* src = qkv + (size_t)b * KK * 3 * CC;
    for (int i = tid; i < KK * 3 * CC; i += 512) sq[i] = src[i];
    __syncthreads();

    const int h = tid >> 6;
    const int lane = tid & 63;
    const float scl = rsqrtf((float)HD);

    if (lane < KK * KK) {
        const int n = lane / KK, m = lane - (lane / KK) * KK;
        const float* qp = &sq[n * (3 * CC) + 0 * CC + h * HD];
        const float* kp = &sq[m * (3 * CC) + 1 * CC + h * HD];
        float s = 0.0f;
#pragma unroll 4
        for (int d = 0; d < HD; ++d) s += qp[d] * kp[d];
        sp[h][lane] = s * scl;
    }
    __syncthreads();
    if (lane < KK) {
        const int n = lane;
        float mx = -1e30f;
#pragma unroll
        for (int m = 0; m < KK; ++m) mx = fmaxf(mx, sp[h][n * KK + m]);
        float e[KK];
        float sum = 0.0f;
#pragma unroll
        for (int m = 0; m < KK; ++m) { e[m] = expf(sp[h][n * KK + m] - mx); sum += e[m]; }
        const float inv = 1.0f / sum;
#pragma unroll
        for (int m = 0; m < KK; ++m) sp[h][n * KK + m] = e[m] * inv;
    }
    __syncthreads();
    for (int i = tid; i < KK * CC; i += 512) {
        const int n = i / CC;
        const int cd = i - n * CC;
        const int hh = cd / HD;
        const int d = cd - hh * HD;
        float acc = 0.0f;
#pragma unroll
        for (int m = 0; m < KK; ++m)
            acc += sp[hh][n * KK + m] * sq[m * (3 * CC) + 2 * CC + hh * HD + d];
        o[(size_t)b * KK * CC + i] = f2b(acc);
    }
}

// ---------------------------------------------------------------------------
// Final: LN(t) with lnf, then out[b,c] = sum_k tln[b,k,c]*wm2_w[k] + wm2_b
// one block per b
// ---------------------------------------------------------------------------
__global__ __launch_bounds__(256) void final_kernel(
    const float* __restrict__ t,     // B*6*544
    const float* __restrict__ g,
    const float* __restrict__ bta,
    const float* __restrict__ wm2w,  // 6
    const float* __restrict__ wm2b,  // 1
    float* __restrict__ out)         // B*544
{
    const int b = blockIdx.x;
    const int tid = threadIdx.x;
    __shared__ float st[KK][CC];
    __shared__ float sm[KK], si[KK];
    const float* tb = t + (size_t)b * KK * CC;
    for (int i = tid; i < KK * CC; i += 256) st[i / CC][i % CC] = tb[i];
    __syncthreads();
    const int wid = tid >> 6, lane = tid & 63;
    for (int r = wid; r < KK; r += 4) {
        float s = 0.0f, s2 = 0.0f;
        for (int c = lane; c < CC; c += 64) { const float v = st[r][c]; s += v; s2 += v * v; }
#pragma unroll
        for (int off = 32; off; off >>= 1) { s += __shfl_down(s, off); s2 += __shfl_down(s2, off); }
        if (lane == 0) {
            const float m = s / (float)CC;
            const float var = s2 / (float)CC - m * m;
            sm[r] = m;
            si[r] = rsqrtf(var + EPSF);
        }
    }
    __syncthreads();
    const float w0 = wm2w[0], w1 = wm2w[1], w2 = wm2w[2], w3 = wm2w[3], w4 = wm2w[4], w5 = wm2w[5];
    const float wb = wm2b[0];
    for (int c = tid; c < CC; c += 256) {
        const float gg = g[c], bb = bta[c];
        float acc = wb;
        acc += w0 * ((st[0][c] - sm[0]) * si[0] * gg + bb);
        acc += w1 * ((st[1][c] - sm[1]) * si[1] * gg + bb);
        acc += w2 * ((st[2][c] - sm[2]) * si[2] * gg + bb);
        acc += w3 * ((st[3][c] - sm[3]) * si[3] * gg + bb);
        acc += w4 * ((st[4][c] - sm[4]) * si[4] * gg + bb);
        acc += w5 * ((st[5][c] - sm[5]) * si[5] * gg + bb);
        out[(size_t)b * CC + c] = acc;
    }
}

// ---------------------------------------------------------------------------
extern "C" void kernel_launch(void* const* d_in, const int* in_sizes, int n_in,
                              void* d_out, int out_size, void* d_ws, size_t ws_size,
                              hipStream_t stream)
{
    const float* x      = (const float*)d_in[0];
    const float* pos    = (const float*)d_in[1];
    const float* fc1_w  = (const float*)d_in[2];
    const float* fc2_w  = (const float*)d_in[3];
    const float* ln1_g  = (const float*)d_in[4];
    const float* ln1_b  = (const float*)d_in[5];
    const float* qkv_w  = (const float*)d_in[6];
    const float* qkv_b  = (const float*)d_in[7];
    const float* proj_w = (const float*)d_in[8];
    const float* proj_b = (const float*)d_in[9];
    const float* ln2_g  = (const float*)d_in[10];
    const float* ln2_b  = (const float*)d_in[11];
    const float* mfc1_w = (const float*)d_in[12];
    const float* mfc1_b = (const float*)d_in[13];
    const float* mfc2_w = (const float*)d_in[14];
    const float* mfc2_b = (const float*)d_in[15];
    const float* lnf_g  = (const float*)d_in[16];
    const float* lnf_b  = (const float*)d_in[17];
    const float* wm2_w  = (const float*)d_in[18];
    const float* wm2_b  = (const float*)d_in[19];

    float* ws = (float*)d_ws;
    float* L    = ws;                              // 124416
    float* R    = L + 124416;                      // 124416
    float* t    = R + 124416;                      // 3072*544
    float* qkvb = t + (size_t)MTOK * CC;           // 3072*1632 f32
    unsigned short* hb  = (unsigned short*)(qkvb + (size_t)MTOK * 3 * CC);  // 3072*544 bf16
    unsigned short* ob  = hb + (size_t)MTOK * CC;                            // 3072*544 bf16
    unsigned short* gb  = ob + (size_t)MTOK * CC;                            // 3072*1088 bf16
    unsigned short* wbf = gb + (size_t)MTOK * HID;                           // 4,734,976 bf16

    // weight bf16 sub-pointers (element offsets within wbf)
    unsigned short* wqkv = wbf;                         // 2 x (1632*544)
    unsigned short* wprj = wbf + 1775616;               // 2 x (544*544)
    unsigned short* wf1  = wbf + 2367488;               // 2 x (1088*544)
    unsigned short* wf2  = wbf + 3551232;               // 2 x (544*1088)

    wconv_kernel<<<4624, 256, 0, stream>>>(qkv_w, proj_w, mfc1_w, mfc2_w, (__hip_bfloat16*)wbf);
    rowsum_kernel<<<31104, 256, 0, stream>>>(x, pos, L, R);
    select_kernel<<<BB, 128, 0, stream>>>(L, R, fc1_w, fc2_w, x, pos, t);

    for (int i = 0; i < DEPTH; ++i) {
        ln_bf16_kernel<<<MTOK, 256, 0, stream>>>(t, ln1_g + i * CC, ln1_b + i * CC, (__hip_bfloat16*)hb);
        gemm_mfma_kernel<0, 0, 0><<<dim3(13, 24), 256, 0, stream>>>(
            hb, wqkv + (size_t)i * 1632 * 544, qkv_b + (size_t)i * 3 * CC,
            nullptr, qkvb, MTOK, 3 * CC, CC);
        attn_kernel<<<BB, 512, 0, stream>>>(qkvb, (__hip_bfloat16*)ob);
        gemm_mfma_kernel<0, 1, 0><<<dim3(5, 24), 256, 0, stream>>>(
            ob, wprj + (size_t)i * 544 * 544, proj_b + (size_t)i * CC,
            t, t, MTOK, CC, CC);
        ln_bf16_kernel<<<MTOK, 256, 0, stream>>>(t, ln2_g + i * CC, ln2_b + i * CC, (__hip_bfloat16*)hb);
        gemm_mfma_kernel<1, 0, 1><<<dim3(9, 24), 256, 0, stream>>>(
            hb, wf1 + (size_t)i * HID * 544, mfc1_b + (size_t)i * HID,
            nullptr, gb, MTOK, HID, CC);
        gemm_mfma_kernel<0, 1, 0><<<dim3(5, 24), 256, 0, stream>>>(
            gb, wf2 + (size_t)i * 544 * HID, mfc2_b + (size_t)i * CC,
            t, t, MTOK, CC, HID);
    }

    final_kernel<<<BB, 256, 0, stream>>>(t, lnf_g, lnf_b, wm2_w, wm2_b, (float*)d_out);
}

// Round 3
// 309.650 us; speedup vs baseline: 2.4959x; 1.0429x over previous
//
#include <hip/hip_runtime.h>
#include <hip/hip_bf16.h>
#include <math.h>

// Problem constants
#define TT 243
#define CC 544            // J*IC
#define NBB 81            // T/BS
#define KK 6
#define HH 8
#define HD 68             // C/H
#define DEPTH 2
#define HID 1088          // 2*C
#define BB 512
#define MTOK 3072         // B*K tokens
#define EPSF 1e-6f

typedef __attribute__((ext_vector_type(8))) short bf16x8;
typedef __attribute__((ext_vector_type(4))) float f32x4;

__device__ __forceinline__ __hip_bfloat16 f2b(float f) { return __float2bfloat16(f); }
__device__ __forceinline__ unsigned short f2bu(float f) {
    __hip_bfloat16 h = __float2bfloat16(f);
    return *(unsigned short*)&h;
}

// weight conversion segment ends (float4-index space): qkv | proj | mfc1 | mfc2
#define E0 443904      // 2*1632*544/4
#define E1 591872      // +2*544*544/4
#define E2 887808      // +2*1088*544/4
#define E3 1183744     // +2*544*1088/4
#define WCONV_BLOCKS 1156   // ceil(E3/1024)

// ---------------------------------------------------------------------------
// prep: blocks [0,512): per-b rowsum -> MLP -> top6 -> gather -> t + ln1_0 -> hb
//       blocks [512, 512+1156): weight f32->bf16 conversion
// ---------------------------------------------------------------------------
__global__ __launch_bounds__(1024) void prep_kernel(
    const float* __restrict__ x,     // B*T*C
    const float* __restrict__ pos,   // T*C
    const float* __restrict__ fc1,   // 81*81
    const float* __restrict__ fc2,   // 81*81
    const float* __restrict__ ln1g,  // 544 (layer 0)
    const float* __restrict__ ln1b,  // 544 (layer 0)
    const float* __restrict__ qkvw, const float* __restrict__ projw,
    const float* __restrict__ mfc1w, const float* __restrict__ mfc2w,
    unsigned short* __restrict__ wbf,
    float* __restrict__ t,           // B*6*544 f32
    unsigned short* __restrict__ hb) // B*6*544 bf16 (= ln1_0 output)
{
    const int tid = threadIdx.x;

    if (blockIdx.x >= BB) {
        // ---- weight conversion path ----
        const int i = (blockIdx.x - BB) * 1024 + tid;
        if (i < E3) {
            float4 v;
            if (i < E0)      v = ((const float4*)qkvw)[i];
            else if (i < E1) v = ((const float4*)projw)[i - E0];
            else if (i < E2) v = ((const float4*)mfc1w)[i - E1];
            else             v = ((const float4*)mfc2w)[i - E2];
            ushort4 o;
            o.x = f2bu(v.x); o.y = f2bu(v.y); o.z = f2bu(v.z); o.w = f2bu(v.w);
            ((ushort4*)wbf)[i] = o;
        }
        return;
    }

    const int b = blockIdx.x;
    __shared__ float Ls[TT], Rs[TT];
    __shared__ float sy[NBB], sz[NBB], swv[NBB];
    __shared__ int sidx[KK];
    __shared__ __align__(16) float st[KK][CC];

    const int w = tid >> 6;       // wave 0..15
    const int lane = tid & 63;
    const float4* x4 = (const float4*)x;
    const float4* p4 = (const float4*)pos;

    // rowsum: wave w handles rows w, w+16, ...
    for (int r = w; r < TT; r += 16) {
        float sL = 0.0f, sR = 0.0f;
#pragma unroll
        for (int it = 0; it < 3; ++it) {
            const int c4 = lane + it * 64;
            if (c4 < 136) {
                const float4 xv = x4[((size_t)b * TT + r) * 136 + c4];
                const float4 pv = p4[(size_t)r * 136 + c4];
                const float s = (xv.x + pv.x) + (xv.y + pv.y) + (xv.z + pv.z) + (xv.w + pv.w);
                if (c4 < 68) sL += s; else sR += s;
            }
        }
#pragma unroll
        for (int off = 32; off; off >>= 1) {
            sL += __shfl_down(sL, off);
            sR += __shfl_down(sR, off);
        }
        if (lane == 0) { Ls[r] = sL; Rs[r] = sR; }
    }
    __syncthreads();

    // y0
    if (tid < NBB) {
        const int n = tid;
        float s = Ls[3 * n] + Ls[3 * n + 1] + Rs[3 * n] + Rs[3 * n + 1] + Rs[3 * n + 2];
        if (n > 0) s += Ls[3 * n - 1];
        sy[n] = s * (1.0f / (3.0f * (float)CC));
    }
    __syncthreads();
    if (tid < NBB) {
        float s = 0.0f;
        for (int j = 0; j < NBB; ++j) s += fc1[tid * NBB + j] * sy[j];
        sz[tid] = fmaxf(s, 0.0f);
    }
    __syncthreads();
    if (tid < NBB) {
        float s = 0.0f;
        for (int j = 0; j < NBB; ++j) s += fc2[tid * NBB + j] * sz[j];
        swv[tid] = 1.0f / (1.0f + expf(-s));
    }
    __syncthreads();
    if (tid == 0) {
        unsigned long long used0 = 0ull, used1 = 0ull;
        for (int kk = 0; kk < KK; ++kk) {
            float best = -1e30f;
            int bi = 0;
            for (int j = 0; j < NBB; ++j) {
                const bool u = (j < 64) ? ((used0 >> j) & 1ull) : ((used1 >> (j - 64)) & 1ull);
                if (!u && swv[j] > best) { best = swv[j]; bi = j; }
            }
            sidx[kk] = bi;
            if (bi < 64) used0 |= (1ull << bi); else used1 |= (1ull << (bi - 64));
        }
    }
    __syncthreads();

    // gather -> st (LDS) + t (global f32)
    if (tid < KK * 136) {
        const int k = tid / 136;
        const int c4 = tid - k * 136;
        const int n = sidx[k];
        const int shift = (c4 < 68) ? -1 : 0;
        float ax = 0.f, ay = 0.f, az = 0.f, aw = 0.f;
#pragma unroll
        for (int i2 = 0; i2 < 3; ++i2) {
            const int ttr = 3 * n + i2 + shift;
            if (ttr >= 0) {
                const float4 xv = x4[((size_t)b * TT + ttr) * 136 + c4];
                const float4 pv = p4[(size_t)ttr * 136 + c4];
                ax += xv.x + pv.x; ay += xv.y + pv.y; az += xv.z + pv.z; aw += xv.w + pv.w;
            }
        }
        const float inv3 = 1.0f / 3.0f;
        const float4 a = make_float4(ax * inv3, ay * inv3, az * inv3, aw * inv3);
        *(float4*)&st[k][c4 * 4] = a;
        ((float4*)t)[((size_t)b * KK + k) * 136 + c4] = a;
    }
    __syncthreads();

    // ln1 (layer 0) per row k = wave
    if (w < KK) {
        float s = 0.0f, s2 = 0.0f;
        for (int c = lane; c < CC; c += 64) { const float v = st[w][c]; s += v; s2 += v * v; }
#pragma unroll
        for (int off = 32; off; off >>= 1) {
            s += __shfl_down(s, off);
            s2 += __shfl_down(s2, off);
        }
        s = __shfl(s, 0);
        s2 = __shfl(s2, 0);
        const float m = s / (float)CC;
        const float inv = rsqrtf(s2 / (float)CC - m * m + EPSF);
        for (int c4 = lane; c4 < 136; c4 += 64) {
            const float4 v = *(const float4*)&st[w][c4 * 4];
            const float4 gv = ((const float4*)ln1g)[c4];
            const float4 bv = ((const float4*)ln1b)[c4];
            ushort4 o;
            o.x = f2bu((v.x - m) * inv * gv.x + bv.x);
            o.y = f2bu((v.y - m) * inv * gv.y + bv.y);
            o.z = f2bu((v.z - m) * inv * gv.z + bv.z);
            o.w = f2bu((v.w - m) * inv * gv.w + bv.w);
            ((ushort4*)hb)[((size_t)b * KK + w) * 136 + c4] = o;
        }
    }
}

// ---------------------------------------------------------------------------
// LayerNorm over last dim (544), vectorized, output bf16
// ---------------------------------------------------------------------------
__global__ __launch_bounds__(256) void ln_bf16_kernel(
    const float* __restrict__ X,   // M x 544
    const float* __restrict__ g,   // 544
    const float* __restrict__ bta, // 544
    unsigned short* __restrict__ Y)
{
    const int row = blockIdx.x;
    const int tid = threadIdx.x;
    const float4* xr4 = (const float4*)(X + (size_t)row * CC);
    float4 v = make_float4(0.f, 0.f, 0.f, 0.f);
    if (tid < 136) v = xr4[tid];
    float s = v.x + v.y + v.z + v.w;
    float s2 = v.x * v.x + v.y * v.y + v.z * v.z + v.w * v.w;
#pragma unroll
    for (int off = 32; off; off >>= 1) {
        s += __shfl_down(s, off);
        s2 += __shfl_down(s2, off);
    }
    __shared__ float sa[4], sb[4];
    __shared__ float mean_s, inv_s;
    const int wid = tid >> 6, lane = tid & 63;
    if (lane == 0) { sa[wid] = s; sb[wid] = s2; }
    __syncthreads();
    if (tid == 0) {
        const float S = sa[0] + sa[1] + sa[2] + sa[3];
        const float S2 = sb[0] + sb[1] + sb[2] + sb[3];
        const float m = S / (float)CC;
        mean_s = m;
        inv_s = rsqrtf(S2 / (float)CC - m * m + EPSF);
    }
    __syncthreads();
    if (tid < 136) {
        const float m = mean_s, inv = inv_s;
        const float4 gv = ((const float4*)g)[tid];
        const float4 bv = ((const float4*)bta)[tid];
        ushort4 o;
        o.x = f2bu((v.x - m) * inv * gv.x + bv.x);
        o.y = f2bu((v.y - m) * inv * gv.y + bv.y);
        o.z = f2bu((v.z - m) * inv * gv.z + bv.z);
        o.w = f2bu((v.w - m) * inv * gv.w + bv.w);
        ((ushort4*)(Y + (size_t)row * CC))[tid] = o;
    }
}

// ---------------------------------------------------------------------------
// bf16 MFMA GEMM: Y[M,N] = act(Xbf[M,K] @ Wbf[N,K]^T + bias[N]) (+R) (f32/bf16 out)
// 128x128 tile, BK=32, 256 threads = 4 waves (2x2), wave tile 64x64
// ---------------------------------------------------------------------------
template <int ACT, int RES, int OBF>
__global__ __launch_bounds__(256) void gemm_mfma_kernel(
    const unsigned short* __restrict__ X,   // bf16 M x K
    const unsigned short* __restrict__ W,   // bf16 N x K
    const float* __restrict__ bias,         // N
    const float* __restrict__ R,            // M x N (f32) or null
    void* __restrict__ Y,                   // f32 or bf16
    int M, int N, int Kd)
{
    const int bm = blockIdx.y * 128;
    const int bn = blockIdx.x * 128;
    const int tid = threadIdx.x;
    const int K8 = Kd >> 3;    // uint4 per row

    __shared__ __align__(16) short As[128][40];
    __shared__ __align__(16) short Bs[128][40];

    const int r0 = tid >> 2;           // rows 0..63
    const int c0 = tid & 3;            // chunk 0..3
    const int r1 = r0 + 64;            // rows 64..127

    const uint4* Xu = (const uint4*)X;
    const uint4* Wu = (const uint4*)W;

    const int wid = tid >> 6;
    const int lane = tid & 63;
    const int wm = (wid >> 1) * 64;
    const int wn = (wid & 1) * 64;
    const int l16 = lane & 15;
    const int l4 = lane >> 4;          // 0..3
    const int koff = l4 * 8;

    f32x4 acc[4][4] = {};

    const int wr0 = min(bn + r0, N - 1);
    const int wr1 = min(bn + r1, N - 1);

    uint4 a0 = Xu[(size_t)(bm + r0) * K8 + c0];
    uint4 a1 = Xu[(size_t)(bm + r1) * K8 + c0];
    uint4 b0 = Wu[(size_t)wr0 * K8 + c0];
    uint4 b1 = Wu[(size_t)wr1 * K8 + c0];

    const int nk = Kd >> 5;
    for (int kt = 0; kt < nk; ++kt) {
        __syncthreads();
        *(uint4*)&As[r0][c0 * 8] = a0;
        *(uint4*)&As[r1][c0 * 8] = a1;
        *(uint4*)&Bs[r0][c0 * 8] = b0;
        *(uint4*)&Bs[r1][c0 * 8] = b1;
        __syncthreads();

        const bool more = (kt + 1 < nk);
        uint4 na0, na1, nb0, nb1;
        if (more) {
            const int kc = (kt + 1) * 4 + c0;
            na0 = Xu[(size_t)(bm + r0) * K8 + kc];
            na1 = Xu[(size_t)(bm + r1) * K8 + kc];
            nb0 = Wu[(size_t)wr0 * K8 + kc];
            nb1 = Wu[(size_t)wr1 * K8 + kc];
        }

        bf16x8 af[4], bf[4];
#pragma unroll
        for (int mf = 0; mf < 4; ++mf) af[mf] = *(const bf16x8*)&As[wm + mf * 16 + l16][koff];
#pragma unroll
        for (int nf = 0; nf < 4; ++nf) bf[nf] = *(const bf16x8*)&Bs[wn + nf * 16 + l16][koff];
#pragma unroll
        for (int mf = 0; mf < 4; ++mf)
#pragma unroll
            for (int nf = 0; nf < 4; ++nf)
                acc[mf][nf] = __builtin_amdgcn_mfma_f32_16x16x32_bf16(af[mf], bf[nf], acc[mf][nf], 0, 0, 0);

        if (more) { a0 = na0; a1 = na1; b0 = nb0; b1 = nb1; }
    }

    // epilogue
#pragma unroll
    for (int nf = 0; nf < 4; ++nf) {
        const int col = bn + wn + nf * 16 + l16;
        if (col < N) {
            const float bs = bias[col];
#pragma unroll
            for (int mf = 0; mf < 4; ++mf) {
#pragma unroll
                for (int j = 0; j < 4; ++j) {
                    const int row = bm + wm + mf * 16 + l4 * 4 + j;
                    float v = acc[mf][nf][j] + bs;
                    if (ACT == 1) v = 0.5f * v * (1.0f + erff(v * 0.70710678118654752f));
                    if (RES) v += R[(size_t)row * N + col];
                    if (OBF) ((__hip_bfloat16*)Y)[(size_t)row * N + col] = f2b(v);
                    else     ((float*)Y)[(size_t)row * N + col] = v;
                }
            }
        }
    }
}

// ---------------------------------------------------------------------------
// Attention: per block b; 8 waves = 8 heads; 6 tokens, head dim 68; out bf16
// ---------------------------------------------------------------------------
__global__ __launch_bounds__(512) void attn_kernel(
    const float* __restrict__ qkv,       // B*6*1632 f32
    __hip_bfloat16* __restrict__ o)      // B*6*544 bf16
{
    const int b = blockIdx.x;
    __shared__ __align__(16) float sq[KK * 3 * CC];
    __shared__ float sp[HH][40];
    const int tid = threadIdx.x;

    const float4* src4 = (const float4*)(qkv + (size_t)b * KK * 3 * CC);
    for (int i = tid; i < KK * 3 * CC / 4; i += 512) ((float4*)sq)[i] = src4[i];
    __syncthreads();

    const int h = tid >> 6;
    const int lane = tid & 63;
    const float scl = rsqrtf((float)HD);

    if (lane < KK * KK) {
        const int n = lane / KK, m = lane - (lane / KK) * KK;
        const float* qp = &sq[n * (3 * CC) + 0 * CC + h * HD];
        const float* kp = &sq[m * (3 * CC) + 1 * CC + h * HD];
        float s = 0.0f;
#pragma unroll 4
        for (int d = 0; d < HD; ++d) s += qp[d] * kp[d];
        sp[h][lane] = s * scl;
    }
    __syncthreads();
    if (lane < KK) {
        const int n = lane;
        float mx = -1e30f;
#pragma unroll
        for (int m = 0; m < KK; ++m) mx = fmaxf(mx, sp[h][n * KK + m]);
        float e[KK];
        float sum = 0.0f;
#pragma unroll
        for (int m = 0; m < KK; ++m) { e[m] = expf(sp[h][n * KK + m] - mx); sum += e[m]; }
        const float inv = 1.0f / sum;
#pragma unroll
        for (int m = 0; m < KK; ++m) sp[h][n * KK + m] = e[m] * inv;
    }
    __syncthreads();
    for (int i = tid; i < KK * CC; i += 512) {
        const int n = i / CC;
        const int cd = i - n * CC;
        const int hh = cd / HD;
        const int d = cd - hh * HD;
        float acc = 0.0f;
#pragma unroll
        for (int m = 0; m < KK; ++m)
            acc += sp[hh][n * KK + m] * sq[m * (3 * CC) + 2 * CC + hh * HD + d];
        o[(size_t)b * KK * CC + i] = f2b(acc);
    }
}

// ---------------------------------------------------------------------------
// Final: LN(t) with lnf, then out[b,c] = sum_k tln[b,k,c]*wm2_w[k] + wm2_b
// ---------------------------------------------------------------------------
__global__ __launch_bounds__(256) void final_kernel(
    const float* __restrict__ t,     // B*6*544
    const float* __restrict__ g,
    const float* __restrict__ bta,
    const float* __restrict__ wm2w,  // 6
    const float* __restrict__ wm2b,  // 1
    float* __restrict__ out)         // B*544
{
    const int b = blockIdx.x;
    const int tid = threadIdx.x;
    __shared__ float st[KK][CC];
    __shared__ float sm[KK], si[KK];
    const float* tb = t + (size_t)b * KK * CC;
    for (int i = tid; i < KK * CC; i += 256) st[i / CC][i % CC] = tb[i];
    __syncthreads();
    const int wid = tid >> 6, lane = tid & 63;
    for (int r = wid; r < KK; r += 4) {
        float s = 0.0f, s2 = 0.0f;
        for (int c = lane; c < CC; c += 64) { const float v = st[r][c]; s += v; s2 += v * v; }
#pragma unroll
        for (int off = 32; off; off >>= 1) { s += __shfl_down(s, off); s2 += __shfl_down(s2, off); }
        if (lane == 0) {
            const float m = s / (float)CC;
            sm[r] = m;
            si[r] = rsqrtf(s2 / (float)CC - m * m + EPSF);
        }
    }
    __syncthreads();
    const float w0 = wm2w[0], w1 = wm2w[1], w2 = wm2w[2], w3 = wm2w[3], w4 = wm2w[4], w5 = wm2w[5];
    const float wb = wm2b[0];
    for (int c = tid; c < CC; c += 256) {
        const float gg = g[c], bb = bta[c];
        float acc = wb;
        acc += w0 * ((st[0][c] - sm[0]) * si[0] * gg + bb);
        acc += w1 * ((st[1][c] - sm[1]) * si[1] * gg + bb);
        acc += w2 * ((st[2][c] - sm[2]) * si[2] * gg + bb);
        acc += w3 * ((st[3][c] - sm[3]) * si[3] * gg + bb);
        acc += w4 * ((st[4][c] - sm[4]) * si[4] * gg + bb);
        acc += w5 * ((st[5][c] - sm[5]) * si[5] * gg + bb);
        out[(size_t)b * CC + c] = acc;
    }
}

// ---------------------------------------------------------------------------
extern "C" void kernel_launch(void* const* d_in, const int* in_sizes, int n_in,
                              void* d_out, int out_size, void* d_ws, size_t ws_size,
                              hipStream_t stream)
{
    const float* x      = (const float*)d_in[0];
    const float* pos    = (const float*)d_in[1];
    const float* fc1_w  = (const float*)d_in[2];
    const float* fc2_w  = (const float*)d_in[3];
    const float* ln1_g  = (const float*)d_in[4];
    const float* ln1_b  = (const float*)d_in[5];
    const float* qkv_w  = (const float*)d_in[6];
    const float* qkv_b  = (const float*)d_in[7];
    const float* proj_w = (const float*)d_in[8];
    const float* proj_b = (const float*)d_in[9];
    const float* ln2_g  = (const float*)d_in[10];
    const float* ln2_b  = (const float*)d_in[11];
    const float* mfc1_w = (const float*)d_in[12];
    const float* mfc1_b = (const float*)d_in[13];
    const float* mfc2_w = (const float*)d_in[14];
    const float* mfc2_b = (const float*)d_in[15];
    const float* lnf_g  = (const float*)d_in[16];
    const float* lnf_b  = (const float*)d_in[17];
    const float* wm2_w  = (const float*)d_in[18];
    const float* wm2_b  = (const float*)d_in[19];

    float* ws = (float*)d_ws;
    float* t    = ws;                              // 3072*544 f32
    float* qkvb = t + (size_t)MTOK * CC;           // 3072*1632 f32
    unsigned short* hb  = (unsigned short*)(qkvb + (size_t)MTOK * 3 * CC);  // 3072*544 bf16
    unsigned short* ob  = hb + (size_t)MTOK * CC;                            // 3072*544 bf16
    unsigned short* gb  = ob + (size_t)MTOK * CC;                            // 3072*1088 bf16
    unsigned short* wbf = gb + (size_t)MTOK * HID;                           // 4,734,976 bf16

    unsigned short* wqkv = wbf;                         // 2 x (1632*544)
    unsigned short* wprj = wbf + 1775616;               // 2 x (544*544)
    unsigned short* wf1  = wbf + 2367488;               // 2 x (1088*544)
    unsigned short* wf2  = wbf + 3551232;               // 2 x (544*1088)

    // mega prep: rowsum + MLP + top6 + gather + ln1_0  ||  weight conversion
    prep_kernel<<<BB + WCONV_BLOCKS, 1024, 0, stream>>>(
        x, pos, fc1_w, fc2_w, ln1_g, ln1_b,
        qkv_w, proj_w, mfc1_w, mfc2_w, wbf, t, hb);

    for (int i = 0; i < DEPTH; ++i) {
        if (i > 0) {
            ln_bf16_kernel<<<MTOK, 256, 0, stream>>>(t, ln1_g + i * CC, ln1_b + i * CC, hb);
        }
        gemm_mfma_kernel<0, 0, 0><<<dim3(13, 24), 256, 0, stream>>>(
            hb, wqkv + (size_t)i * 1632 * 544, qkv_b + (size_t)i * 3 * CC,
            nullptr, qkvb, MTOK, 3 * CC, CC);
        attn_kernel<<<BB, 512, 0, stream>>>(qkvb, (__hip_bfloat16*)ob);
        gemm_mfma_kernel<0, 1, 0><<<dim3(5, 24), 256, 0, stream>>>(
            ob, wprj + (size_t)i * 544 * 544, proj_b + (size_t)i * CC,
            t, t, MTOK, CC, CC);
        ln_bf16_kernel<<<MTOK, 256, 0, stream>>>(t, ln2_g + i * CC, ln2_b + i * CC, hb);
        gemm_mfma_kernel<1, 0, 1><<<dim3(9, 24), 256, 0, stream>>>(
            hb, wf1 + (size_t)i * HID * 544, mfc1_b + (size_t)i * HID,
            nullptr, gb, MTOK, HID, CC);
        gemm_mfma_kernel<0, 1, 0><<<dim3(5, 24), 256, 0, stream>>>(
            gb, wf2 + (size_t)i * 544 * HID, mfc2_b + (size_t)i * CC,
            t, t, MTOK, CC, HID);
    }

    final_kernel<<<BB, 256, 0, stream>>>(t, lnf_g, lnf_b, wm2_w, wm2_b, (float*)d_out);
}

// Round 4
// 290.418 us; speedup vs baseline: 2.6612x; 1.0662x over previous
//
#include <hip/hip_runtime.h>
#include <hip/hip_bf16.h>
#include <math.h>

// Problem constants
#define TT 243
#define CC 544            // J*IC
#define NBB 81            // T/BS
#define KK 6
#define HH 8
#define HD 68             // C/H
#define DEPTH 2
#define HID 1088          // 2*C
#define BB 512
#define MTOK 3072         // B*K tokens
#define EPSF 1e-6f

typedef __attribute__((ext_vector_type(8))) short bf16x8;
typedef __attribute__((ext_vector_type(4))) float f32x4;

__device__ __forceinline__ __hip_bfloat16 f2b(float f) { return __float2bfloat16(f); }
__device__ __forceinline__ unsigned short f2bu(float f) {
    __hip_bfloat16 h = __float2bfloat16(f);
    return *(unsigned short*)&h;
}
__device__ __forceinline__ float b2f_lo(unsigned int u) { return __uint_as_float(u << 16); }
__device__ __forceinline__ float b2f_hi(unsigned int u) { return __uint_as_float(u & 0xffff0000u); }

// weight conversion segment ends (float4-index space): qkv | proj | mfc1 | mfc2
#define E0 443904      // 2*1632*544/4
#define E1 591872      // +2*544*544/4
#define E2 887808      // +2*1088*544/4
#define E3 1183744     // +2*544*1088/4
#define WCONV_BLOCKS 1156   // ceil(E3/1024)

// ---------------------------------------------------------------------------
// prep: blocks [0,512): per-b rowsum -> MLP -> top6 -> gather -> t + ln1_0 -> hb
//       blocks [512, 512+1156): weight f32->bf16 conversion
// ---------------------------------------------------------------------------
__global__ __launch_bounds__(1024) void prep_kernel(
    const float* __restrict__ x,     // B*T*C
    const float* __restrict__ pos,   // T*C
    const float* __restrict__ fc1,   // 81*81
    const float* __restrict__ fc2,   // 81*81
    const float* __restrict__ ln1g,  // 544 (layer 0)
    const float* __restrict__ ln1b,  // 544 (layer 0)
    const float* __restrict__ qkvw, const float* __restrict__ projw,
    const float* __restrict__ mfc1w, const float* __restrict__ mfc2w,
    unsigned short* __restrict__ wbf,
    float* __restrict__ t,           // B*6*544 f32
    unsigned short* __restrict__ hb) // B*6*544 bf16 (= ln1_0 output)
{
    const int tid = threadIdx.x;

    if (blockIdx.x >= BB) {
        // ---- weight conversion path ----
        const int i = (blockIdx.x - BB) * 1024 + tid;
        if (i < E3) {
            float4 v;
            if (i < E0)      v = ((const float4*)qkvw)[i];
            else if (i < E1) v = ((const float4*)projw)[i - E0];
            else if (i < E2) v = ((const float4*)mfc1w)[i - E1];
            else             v = ((const float4*)mfc2w)[i - E2];
            ushort4 o;
            o.x = f2bu(v.x); o.y = f2bu(v.y); o.z = f2bu(v.z); o.w = f2bu(v.w);
            ((ushort4*)wbf)[i] = o;
        }
        return;
    }

    const int b = blockIdx.x;
    __shared__ float Ls[TT], Rs[TT];
    __shared__ float sy[NBB], sz[NBB], swv[NBB];
    __shared__ int sidx[KK];
    __shared__ __align__(16) float st[KK][CC];

    const int w = tid >> 6;       // wave 0..15
    const int lane = tid & 63;
    const int oct = lane & 7;     // 8 lanes per row
    const int rsub = lane >> 3;   // 0..7: row within wave-octet group
    const float4* x4 = (const float4*)x;
    const float4* p4 = (const float4*)pos;

    // rowsum: 2 passes x (16 waves x 8 rows). 17 guard-free float4 per lane.
#pragma unroll
    for (int p = 0; p < 2; ++p) {
        const int row = p * 128 + w * 8 + rsub;
        const int rowc = (row < TT) ? row : (TT - 1);
        const float4* xr = x4 + ((size_t)b * TT + rowc) * 136;
        const float4* pr = p4 + (size_t)rowc * 136;
        float aL = 0.0f, aR = 0.0f;
#pragma unroll
        for (int j = 0; j < 17; ++j) {
            const float4 xv = xr[oct + j * 8];
            const float4 pv = pr[oct + j * 8];
            const float s = (xv.x + pv.x) + (xv.y + pv.y) + (xv.z + pv.z) + (xv.w + pv.w);
            if (j < 8) aL += s;
            else if (j == 8) { if (oct < 4) aL += s; else aR += s; }
            else aR += s;
        }
#pragma unroll
        for (int m = 1; m < 8; m <<= 1) {
            aL += __shfl_xor(aL, m);
            aR += __shfl_xor(aR, m);
        }
        if (oct == 0 && row < TT) { Ls[row] = aL; Rs[row] = aR; }
    }
    __syncthreads();

    // y0
    if (tid < NBB) {
        const int n = tid;
        float s = Ls[3 * n] + Ls[3 * n + 1] + Rs[3 * n] + Rs[3 * n + 1] + Rs[3 * n + 2];
        if (n > 0) s += Ls[3 * n - 1];
        sy[n] = s * (1.0f / (3.0f * (float)CC));
    }
    __syncthreads();
    if (tid < NBB) {
        float s = 0.0f;
        for (int j = 0; j < NBB; ++j) s += fc1[tid * NBB + j] * sy[j];
        sz[tid] = fmaxf(s, 0.0f);
    }
    __syncthreads();
    if (tid < NBB) {
        float s = 0.0f;
        for (int j = 0; j < NBB; ++j) s += fc2[tid * NBB + j] * sz[j];
        swv[tid] = 1.0f / (1.0f + expf(-s));
    }
    __syncthreads();
    // wave-parallel top-6 (wave 0); tie-break: lowest index (matches top_k)
    if (w == 0) {
        float va = (lane < NBB) ? swv[lane] : -1e30f;
        float vb = (lane + 64 < NBB) ? swv[lane + 64] : -1e30f;
        const int ia = lane, ib = lane + 64;
        for (int kk = 0; kk < KK; ++kk) {
            float v = va; int idx = ia;
            if (vb > v) { v = vb; idx = ib; }
#pragma unroll
            for (int m = 1; m < 64; m <<= 1) {
                const float ov = __shfl_xor(v, m);
                const int oi = __shfl_xor(idx, m);
                if (ov > v || (ov == v && oi < idx)) { v = ov; idx = oi; }
            }
            if (lane == 0) sidx[kk] = idx;
            if (ia == idx) va = -1e30f;
            if (ib == idx) vb = -1e30f;
        }
    }
    __syncthreads();

    // gather -> st (LDS) + t (global f32)
    if (tid < KK * 136) {
        const int k = tid / 136;
        const int c4 = tid - k * 136;
        const int n = sidx[k];
        const int shift = (c4 < 68) ? -1 : 0;
        float ax = 0.f, ay = 0.f, az = 0.f, aw = 0.f;
#pragma unroll
        for (int i2 = 0; i2 < 3; ++i2) {
            const int ttr = 3 * n + i2 + shift;
            if (ttr >= 0) {
                const float4 xv = x4[((size_t)b * TT + ttr) * 136 + c4];
                const float4 pv = p4[(size_t)ttr * 136 + c4];
                ax += xv.x + pv.x; ay += xv.y + pv.y; az += xv.z + pv.z; aw += xv.w + pv.w;
            }
        }
        const float inv3 = 1.0f / 3.0f;
        const float4 a = make_float4(ax * inv3, ay * inv3, az * inv3, aw * inv3);
        *(float4*)&st[k][c4 * 4] = a;
        ((float4*)t)[((size_t)b * KK + k) * 136 + c4] = a;
    }
    __syncthreads();

    // ln1 (layer 0) per row k = wave
    if (w < KK) {
        float s = 0.0f, s2 = 0.0f;
        for (int c = lane; c < CC; c += 64) { const float v = st[w][c]; s += v; s2 += v * v; }
#pragma unroll
        for (int off = 32; off; off >>= 1) {
            s += __shfl_xor(s, off);
            s2 += __shfl_xor(s2, off);
        }
        const float m = s / (float)CC;
        const float inv = rsqrtf(s2 / (float)CC - m * m + EPSF);
        for (int c4 = lane; c4 < 136; c4 += 64) {
            const float4 v = *(const float4*)&st[w][c4 * 4];
            const float4 gv = ((const float4*)ln1g)[c4];
            const float4 bv = ((const float4*)ln1b)[c4];
            ushort4 o;
            o.x = f2bu((v.x - m) * inv * gv.x + bv.x);
            o.y = f2bu((v.y - m) * inv * gv.y + bv.y);
            o.z = f2bu((v.z - m) * inv * gv.z + bv.z);
            o.w = f2bu((v.w - m) * inv * gv.w + bv.w);
            ((ushort4*)hb)[((size_t)b * KK + w) * 136 + c4] = o;
        }
    }
}

// ---------------------------------------------------------------------------
// LayerNorm over last dim (544): 4 rows/block, wave per row, no syncthreads
// ---------------------------------------------------------------------------
__global__ __launch_bounds__(256) void ln_bf16_kernel(
    const float* __restrict__ X,   // M x 544
    const float* __restrict__ g,   // 544
    const float* __restrict__ bta, // 544
    unsigned short* __restrict__ Y)
{
    const int row = blockIdx.x * 4 + (threadIdx.x >> 6);
    const int lane = threadIdx.x & 63;
    const float4* xr4 = (const float4*)(X + (size_t)row * CC);
    const float4 v0 = xr4[lane];
    const float4 v1 = xr4[lane + 64];
    float4 v2 = make_float4(0.f, 0.f, 0.f, 0.f);
    if (lane < 8) v2 = xr4[lane + 128];
    float s = (v0.x + v0.y + v0.z + v0.w) + (v1.x + v1.y + v1.z + v1.w)
            + (v2.x + v2.y + v2.z + v2.w);
    float s2 = (v0.x * v0.x + v0.y * v0.y + v0.z * v0.z + v0.w * v0.w)
             + (v1.x * v1.x + v1.y * v1.y + v1.z * v1.z + v1.w * v1.w)
             + (v2.x * v2.x + v2.y * v2.y + v2.z * v2.z + v2.w * v2.w);
#pragma unroll
    for (int off = 32; off; off >>= 1) {
        s += __shfl_xor(s, off);
        s2 += __shfl_xor(s2, off);
    }
    const float m = s / (float)CC;
    const float inv = rsqrtf(s2 / (float)CC - m * m + EPSF);
    ushort4* yr = (ushort4*)(Y + (size_t)row * CC);
    {
        const float4 gv = ((const float4*)g)[lane];
        const float4 bv = ((const float4*)bta)[lane];
        ushort4 o;
        o.x = f2bu((v0.x - m) * inv * gv.x + bv.x);
        o.y = f2bu((v0.y - m) * inv * gv.y + bv.y);
        o.z = f2bu((v0.z - m) * inv * gv.z + bv.z);
        o.w = f2bu((v0.w - m) * inv * gv.w + bv.w);
        yr[lane] = o;
    }
    {
        const float4 gv = ((const float4*)g)[lane + 64];
        const float4 bv = ((const float4*)bta)[lane + 64];
        ushort4 o;
        o.x = f2bu((v1.x - m) * inv * gv.x + bv.x);
        o.y = f2bu((v1.y - m) * inv * gv.y + bv.y);
        o.z = f2bu((v1.z - m) * inv * gv.z + bv.z);
        o.w = f2bu((v1.w - m) * inv * gv.w + bv.w);
        yr[lane + 64] = o;
    }
    if (lane < 8) {
        const float4 gv = ((const float4*)g)[lane + 128];
        const float4 bv = ((const float4*)bta)[lane + 128];
        ushort4 o;
        o.x = f2bu((v2.x - m) * inv * gv.x + bv.x);
        o.y = f2bu((v2.y - m) * inv * gv.y + bv.y);
        o.z = f2bu((v2.z - m) * inv * gv.z + bv.z);
        o.w = f2bu((v2.w - m) * inv * gv.w + bv.w);
        yr[lane + 128] = o;
    }
}

// ---------------------------------------------------------------------------
// bf16 MFMA GEMM: Y[M,N] = act(Xbf[M,K] @ Wbf[N,K]^T + bias[N]) (+R) (f32/bf16 out)
// 128x128 tile, BK=32, 256 threads = 4 waves (2x2), wave tile 64x64
// ---------------------------------------------------------------------------
template <int ACT, int RES, int OBF>
__global__ __launch_bounds__(256) void gemm_mfma_kernel(
    const unsigned short* __restrict__ X,   // bf16 M x K
    const unsigned short* __restrict__ W,   // bf16 N x K
    const float* __restrict__ bias,         // N
    const float* __restrict__ R,            // M x N (f32) or null
    void* __restrict__ Y,                   // f32 or bf16
    int M, int N, int Kd)
{
    const int bm = blockIdx.y * 128;
    const int bn = blockIdx.x * 128;
    const int tid = threadIdx.x;
    const int K8 = Kd >> 3;    // uint4 per row

    __shared__ __align__(16) short As[128][40];
    __shared__ __align__(16) short Bs[128][40];

    const int r0 = tid >> 2;           // rows 0..63
    const int c0 = tid & 3;            // chunk 0..3
    const int r1 = r0 + 64;            // rows 64..127

    const uint4* Xu = (const uint4*)X;
    const uint4* Wu = (const uint4*)W;

    const int wid = tid >> 6;
    const int lane = tid & 63;
    const int wm = (wid >> 1) * 64;
    const int wn = (wid & 1) * 64;
    const int l16 = lane & 15;
    const int l4 = lane >> 4;          // 0..3
    const int koff = l4 * 8;

    f32x4 acc[4][4] = {};

    const int wr0 = min(bn + r0, N - 1);
    const int wr1 = min(bn + r1, N - 1);

    uint4 a0 = Xu[(size_t)(bm + r0) * K8 + c0];
    uint4 a1 = Xu[(size_t)(bm + r1) * K8 + c0];
    uint4 b0 = Wu[(size_t)wr0 * K8 + c0];
    uint4 b1 = Wu[(size_t)wr1 * K8 + c0];

    const int nk = Kd >> 5;
    for (int kt = 0; kt < nk; ++kt) {
        __syncthreads();
        *(uint4*)&As[r0][c0 * 8] = a0;
        *(uint4*)&As[r1][c0 * 8] = a1;
        *(uint4*)&Bs[r0][c0 * 8] = b0;
        *(uint4*)&Bs[r1][c0 * 8] = b1;
        __syncthreads();

        const bool more = (kt + 1 < nk);
        uint4 na0, na1, nb0, nb1;
        if (more) {
            const int kc = (kt + 1) * 4 + c0;
            na0 = Xu[(size_t)(bm + r0) * K8 + kc];
            na1 = Xu[(size_t)(bm + r1) * K8 + kc];
            nb0 = Wu[(size_t)wr0 * K8 + kc];
            nb1 = Wu[(size_t)wr1 * K8 + kc];
        }

        bf16x8 af[4], bf[4];
#pragma unroll
        for (int mf = 0; mf < 4; ++mf) af[mf] = *(const bf16x8*)&As[wm + mf * 16 + l16][koff];
#pragma unroll
        for (int nf = 0; nf < 4; ++nf) bf[nf] = *(const bf16x8*)&Bs[wn + nf * 16 + l16][koff];
#pragma unroll
        for (int mf = 0; mf < 4; ++mf)
#pragma unroll
            for (int nf = 0; nf < 4; ++nf)
                acc[mf][nf] = __builtin_amdgcn_mfma_f32_16x16x32_bf16(af[mf], bf[nf], acc[mf][nf], 0, 0, 0);

        if (more) { a0 = na0; a1 = na1; b0 = nb0; b1 = nb1; }
    }

    // epilogue
#pragma unroll
    for (int nf = 0; nf < 4; ++nf) {
        const int col = bn + wn + nf * 16 + l16;
        if (col < N) {
            const float bs = bias[col];
#pragma unroll
            for (int mf = 0; mf < 4; ++mf) {
#pragma unroll
                for (int j = 0; j < 4; ++j) {
                    const int row = bm + wm + mf * 16 + l4 * 4 + j;
                    float v = acc[mf][nf][j] + bs;
                    if (ACT == 1) v = 0.5f * v * (1.0f + erff(v * 0.70710678118654752f));
                    if (RES) v += R[(size_t)row * N + col];
                    if (OBF) ((__hip_bfloat16*)Y)[(size_t)row * N + col] = f2b(v);
                    else     ((float*)Y)[(size_t)row * N + col] = v;
                }
            }
        }
    }
}

// ---------------------------------------------------------------------------
// Attention: per block b; 8 waves = 8 heads; 6 tokens, head dim 68
// input qkv in bf16, staged to f32 LDS; out bf16
// ---------------------------------------------------------------------------
__global__ __launch_bounds__(512) void attn_kernel(
    const unsigned short* __restrict__ qkv,  // B*6*1632 bf16
    __hip_bfloat16* __restrict__ o)          // B*6*544 bf16
{
    const int b = blockIdx.x;
    __shared__ __align__(16) float sq[KK * 3 * CC];
    __shared__ float sp[HH][40];
    const int tid = threadIdx.x;

    const uint4* src4 = (const uint4*)(qkv + (size_t)b * KK * 3 * CC);  // 1224 uint4
    for (int i = tid; i < (KK * 3 * CC) / 8; i += 512) {
        const uint4 u = src4[i];
        float4 f0, f1;
        f0.x = b2f_lo(u.x); f0.y = b2f_hi(u.x);
        f0.z = b2f_lo(u.y); f0.w = b2f_hi(u.y);
        f1.x = b2f_lo(u.z); f1.y = b2f_hi(u.z);
        f1.z = b2f_lo(u.w); f1.w = b2f_hi(u.w);
        ((float4*)sq)[2 * i] = f0;
        ((float4*)sq)[2 * i + 1] = f1;
    }
    __syncthreads();

    const int h = tid >> 6;
    const int lane = tid & 63;
    const float scl = rsqrtf((float)HD);

    if (lane < KK * KK) {
        const int n = lane / KK, m = lane - (lane / KK) * KK;
        const float* qp = &sq[n * (3 * CC) + 0 * CC + h * HD];
        const float* kp = &sq[m * (3 * CC) + 1 * CC + h * HD];
        float s = 0.0f;
#pragma unroll 4
        for (int d = 0; d < HD; ++d) s += qp[d] * kp[d];
        sp[h][lane] = s * scl;
    }
    __syncthreads();
    if (lane < KK) {
        const int n = lane;
        float mx = -1e30f;
#pragma unroll
        for (int m = 0; m < KK; ++m) mx = fmaxf(mx, sp[h][n * KK + m]);
        float e[KK];
        float sum = 0.0f;
#pragma unroll
        for (int m = 0; m < KK; ++m) { e[m] = expf(sp[h][n * KK + m] - mx); sum += e[m]; }
        const float inv = 1.0f / sum;
#pragma unroll
        for (int m = 0; m < KK; ++m) sp[h][n * KK + m] = e[m] * inv;
    }
    __syncthreads();
    for (int i = tid; i < KK * CC; i += 512) {
        const int n = i / CC;
        const int cd = i - n * CC;
        const int hh = cd / HD;
        const int d = cd - hh * HD;
        float acc = 0.0f;
#pragma unroll
        for (int m = 0; m < KK; ++m)
            acc += sp[hh][n * KK + m] * sq[m * (3 * CC) + 2 * CC + hh * HD + d];
        o[(size_t)b * KK * CC + i] = f2b(acc);
    }
}

// ---------------------------------------------------------------------------
// Final: LN(t) with lnf, then out[b,c] = sum_k tln[b,k,c]*wm2_w[k] + wm2_b
// ---------------------------------------------------------------------------
__global__ __launch_bounds__(256) void final_kernel(
    const float* __restrict__ t,     // B*6*544
    const float* __restrict__ g,
    const float* __restrict__ bta,
    const float* __restrict__ wm2w,  // 6
    const float* __restrict__ wm2b,  // 1
    float* __restrict__ out)         // B*544
{
    const int b = blockIdx.x;
    const int tid = threadIdx.x;
    __shared__ float st[KK][CC];
    __shared__ float sm[KK], si[KK];
    const float* tb = t + (size_t)b * KK * CC;
    for (int i = tid; i < KK * CC; i += 256) st[i / CC][i % CC] = tb[i];
    __syncthreads();
    const int wid = tid >> 6, lane = tid & 63;
    for (int r = wid; r < KK; r += 4) {
        float s = 0.0f, s2 = 0.0f;
        for (int c = lane; c < CC; c += 64) { const float v = st[r][c]; s += v; s2 += v * v; }
#pragma unroll
        for (int off = 32; off; off >>= 1) { s += __shfl_xor(s, off); s2 += __shfl_xor(s2, off); }
        if (lane == 0) {
            const float m = s / (float)CC;
            sm[r] = m;
            si[r] = rsqrtf(s2 / (float)CC - m * m + EPSF);
        }
    }
    __syncthreads();
    const float w0 = wm2w[0], w1 = wm2w[1], w2 = wm2w[2], w3 = wm2w[3], w4 = wm2w[4], w5 = wm2w[5];
    const float wb = wm2b[0];
    for (int c = tid; c < CC; c += 256) {
        const float gg = g[c], bb = bta[c];
        float acc = wb;
        acc += w0 * ((st[0][c] - sm[0]) * si[0] * gg + bb);
        acc += w1 * ((st[1][c] - sm[1]) * si[1] * gg + bb);
        acc += w2 * ((st[2][c] - sm[2]) * si[2] * gg + bb);
        acc += w3 * ((st[3][c] - sm[3]) * si[3] * gg + bb);
        acc += w4 * ((st[4][c] - sm[4]) * si[4] * gg + bb);
        acc += w5 * ((st[5][c] - sm[5]) * si[5] * gg + bb);
        out[(size_t)b * CC + c] = acc;
    }
}

// ---------------------------------------------------------------------------
extern "C" void kernel_launch(void* const* d_in, const int* in_sizes, int n_in,
                              void* d_out, int out_size, void* d_ws, size_t ws_size,
                              hipStream_t stream)
{
    const float* x      = (const float*)d_in[0];
    const float* pos    = (const float*)d_in[1];
    const float* fc1_w  = (const float*)d_in[2];
    const float* fc2_w  = (const float*)d_in[3];
    const float* ln1_g  = (const float*)d_in[4];
    const float* ln1_b  = (const float*)d_in[5];
    const float* qkv_w  = (const float*)d_in[6];
    const float* qkv_b  = (const float*)d_in[7];
    const float* proj_w = (const float*)d_in[8];
    const float* proj_b = (const float*)d_in[9];
    const float* ln2_g  = (const float*)d_in[10];
    const float* ln2_b  = (const float*)d_in[11];
    const float* mfc1_w = (const float*)d_in[12];
    const float* mfc1_b = (const float*)d_in[13];
    const float* mfc2_w = (const float*)d_in[14];
    const float* mfc2_b = (const float*)d_in[15];
    const float* lnf_g  = (const float*)d_in[16];
    const float* lnf_b  = (const float*)d_in[17];
    const float* wm2_w  = (const float*)d_in[18];
    const float* wm2_b  = (const float*)d_in[19];

    float* ws = (float*)d_ws;
    float* t = ws;                                                   // 3072*544 f32
    unsigned short* qkvb = (unsigned short*)(t + (size_t)MTOK * CC); // 3072*1632 bf16
    unsigned short* hb  = qkvb + (size_t)MTOK * 3 * CC;              // 3072*544 bf16
    unsigned short* ob  = hb + (size_t)MTOK * CC;                    // 3072*544 bf16
    unsigned short* gb  = ob + (size_t)MTOK * CC;                    // 3072*1088 bf16
    unsigned short* wbf = gb + (size_t)MTOK * HID;                   // 4,734,976 bf16

    unsigned short* wqkv = wbf;                         // 2 x (1632*544)
    unsigned short* wprj = wbf + 1775616;               // 2 x (544*544)
    unsigned short* wf1  = wbf + 2367488;               // 2 x (1088*544)
    unsigned short* wf2  = wbf + 3551232;               // 2 x (544*1088)

    // mega prep: rowsum + MLP + top6 + gather + ln1_0  ||  weight conversion
    prep_kernel<<<BB + WCONV_BLOCKS, 1024, 0, stream>>>(
        x, pos, fc1_w, fc2_w, ln1_g, ln1_b,
        qkv_w, proj_w, mfc1_w, mfc2_w, wbf, t, hb);

    for (int i = 0; i < DEPTH; ++i) {
        if (i > 0) {
            ln_bf16_kernel<<<MTOK / 4, 256, 0, stream>>>(t, ln1_g + i * CC, ln1_b + i * CC, hb);
        }
        gemm_mfma_kernel<0, 0, 1><<<dim3(13, 24), 256, 0, stream>>>(
            hb, wqkv + (size_t)i * 1632 * 544, qkv_b + (size_t)i * 3 * CC,
            nullptr, qkvb, MTOK, 3 * CC, CC);
        attn_kernel<<<BB, 512, 0, stream>>>(qkvb, (__hip_bfloat16*)ob);
        gemm_mfma_kernel<0, 1, 0><<<dim3(5, 24), 256, 0, stream>>>(
            ob, wprj + (size_t)i * 544 * 544, proj_b + (size_t)i * CC,
            t, t, MTOK, CC, CC);
        ln_bf16_kernel<<<MTOK / 4, 256, 0, stream>>>(t, ln2_g + i * CC, ln2_b + i * CC, hb);
        gemm_mfma_kernel<1, 0, 1><<<dim3(9, 24), 256, 0, stream>>>(
            hb, wf1 + (size_t)i * HID * 544, mfc1_b + (size_t)i * HID,
            nullptr, gb, MTOK, HID, CC);
        gemm_mfma_kernel<0, 1, 0><<<dim3(5, 24), 256, 0, stream>>>(
            gb, wf2 + (size_t)i * 544 * HID, mfc2_b + (size_t)i * CC,
            t, t, MTOK, CC, HID);
    }

    final_kernel<<<BB, 256, 0, stream>>>(t, lnf_g, lnf_b, wm2_w, wm2_b, (float*)d_out);
}

// Round 5
// 272.697 us; speedup vs baseline: 2.8341x; 1.0650x over previous
//
#include <hip/hip_runtime.h>
#include <hip/hip_bf16.h>
#include <math.h>

// Problem constants
#define TT 243
#define CC 544            // J*IC
#define NBB 81            // T/BS
#define KK 6
#define HH 8
#define HD 68             // C/H
#define DEPTH 2
#define HID 1088          // 2*C
#define BB 512
#define MTOK 3072         // B*K tokens
#define EPSF 1e-6f

typedef __attribute__((ext_vector_type(8))) short bf16x8;
typedef __attribute__((ext_vector_type(4))) float f32x4;

__device__ __forceinline__ __hip_bfloat16 f2b(float f) { return __float2bfloat16(f); }
__device__ __forceinline__ unsigned short f2bu(float f) {
    __hip_bfloat16 h = __float2bfloat16(f);
    return *(unsigned short*)&h;
}
__device__ __forceinline__ float b2f_lo(unsigned int u) { return __uint_as_float(u << 16); }
__device__ __forceinline__ float b2f_hi(unsigned int u) { return __uint_as_float(u & 0xffff0000u); }

// weight conversion segment ends (float4-index space): qkv | proj | mfc1 | mfc2
#define E0 443904      // 2*1632*544/4
#define E1 591872      // +2*544*544/4
#define E2 887808      // +2*1088*544/4
#define E3 1183744     // +2*544*1088/4

// bw_kernel block ranges
#define RS_BLOCKS 3888            // 3888*32 rows = 124416 = 512*243
#define PS_BLOCKS 8               // 8*32 = 256 >= 243 pos rows
#define WC_BLOCKS 4624            // E3/256
#define BW_GRID (RS_BLOCKS + PS_BLOCKS + WC_BLOCKS)

// ---------------------------------------------------------------------------
// bw_kernel: pure-bandwidth work in one dispatch.
//  blocks [0, 3888):        x row half-sums (8 lanes/row, 17 reg-buffered loads)
//  blocks [3888, 3896):     pos row half-sums (b-independent, computed once)
//  blocks [3896, 3896+4624): weight f32->bf16 conversion
// ---------------------------------------------------------------------------
__global__ __launch_bounds__(256, 4) void bw_kernel(
    const float* __restrict__ x,     // B*T*C
    const float* __restrict__ pos,   // T*C
    const float* __restrict__ qkvw, const float* __restrict__ projw,
    const float* __restrict__ mfc1w, const float* __restrict__ mfc2w,
    unsigned short* __restrict__ wbf,
    float* __restrict__ L,           // B*T  (x-only)
    float* __restrict__ R,           // B*T  (x-only)
    float* __restrict__ pLR)         // 2*T: pL | pR
{
    const int blk = blockIdx.x;
    const int tid = threadIdx.x;

    if (blk < RS_BLOCKS) {
        const int w = tid >> 6;
        const int lane = tid & 63;
        const int oct = lane & 7;
        const int rsub = lane >> 3;
        const int r = (blk * 4 + w) * 8 + rsub;          // 0..124415
        const float4* xr = (const float4*)x + (size_t)r * 136;
        float4 xs[17];
#pragma unroll
        for (int j = 0; j < 17; ++j) xs[j] = xr[oct + j * 8];
        float aL = 0.0f, aR = 0.0f;
#pragma unroll
        for (int j = 0; j < 17; ++j) {
            const float s = (xs[j].x + xs[j].y) + (xs[j].z + xs[j].w);
            if (j < 8) aL += s;
            else if (j == 8) { if (oct < 4) aL += s; else aR += s; }
            else aR += s;
        }
#pragma unroll
        for (int m = 1; m < 8; m <<= 1) {
            aL += __shfl_xor(aL, m);
            aR += __shfl_xor(aR, m);
        }
        if (oct == 0) { L[r] = aL; R[r] = aR; }
        return;
    }

    if (blk < RS_BLOCKS + PS_BLOCKS) {
        const int w = tid >> 6;
        const int lane = tid & 63;
        const int oct = lane & 7;
        const int rsub = lane >> 3;
        const int r = (blk - RS_BLOCKS) * 32 + w * 8 + rsub;   // 0..255
        const int rc = (r < TT) ? r : (TT - 1);
        const float4* pr = (const float4*)pos + (size_t)rc * 136;
        float4 xs[17];
#pragma unroll
        for (int j = 0; j < 17; ++j) xs[j] = pr[oct + j * 8];
        float aL = 0.0f, aR = 0.0f;
#pragma unroll
        for (int j = 0; j < 17; ++j) {
            const float s = (xs[j].x + xs[j].y) + (xs[j].z + xs[j].w);
            if (j < 8) aL += s;
            else if (j == 8) { if (oct < 4) aL += s; else aR += s; }
            else aR += s;
        }
#pragma unroll
        for (int m = 1; m < 8; m <<= 1) {
            aL += __shfl_xor(aL, m);
            aR += __shfl_xor(aR, m);
        }
        if (oct == 0 && r < TT) { pLR[r] = aL; pLR[TT + r] = aR; }
        return;
    }

    // ---- weight conversion ----
    const int i = (blk - RS_BLOCKS - PS_BLOCKS) * 256 + tid;
    if (i < E3) {
        float4 v;
        if (i < E0)      v = ((const float4*)qkvw)[i];
        else if (i < E1) v = ((const float4*)projw)[i - E0];
        else if (i < E2) v = ((const float4*)mfc1w)[i - E1];
        else             v = ((const float4*)mfc2w)[i - E2];
        ushort4 o;
        o.x = f2bu(v.x); o.y = f2bu(v.y); o.z = f2bu(v.z); o.w = f2bu(v.w);
        ((ushort4*)wbf)[i] = o;
    }
}

// ---------------------------------------------------------------------------
// select: per-b: y0 from L/R(+pos sums), 81x81 MLP x2, sigmoid, top-6,
//         gather t from x+pos, fused ln1 (layer 0) -> hb
// ---------------------------------------------------------------------------
__global__ __launch_bounds__(128) void select_kernel(
    const float* __restrict__ L,     // B*T (x-only)
    const float* __restrict__ R,     // B*T
    const float* __restrict__ pLR,   // 2*T
    const float* __restrict__ fc1,   // 81*81
    const float* __restrict__ fc2,   // 81*81
    const float* __restrict__ x,     // B*T*C
    const float* __restrict__ pos,   // T*C
    const float* __restrict__ ln1g,  // 544 (layer 0)
    const float* __restrict__ ln1b,  // 544 (layer 0)
    float* __restrict__ t,           // B*6*544 f32
    unsigned short* __restrict__ hb) // B*6*544 bf16 (= ln1_0 output)
{
    const int b = blockIdx.x;
    const int tid = threadIdx.x;
    __shared__ float sy[NBB], sz[NBB], swv[NBB];
    __shared__ int sidx[KK];
    __shared__ __align__(16) float st[KK][CC];

    const int w = tid >> 6;
    const int lane = tid & 63;
    const float4* x4 = (const float4*)x;
    const float4* p4 = (const float4*)pos;

    // y0
    if (tid < NBB) {
        const int n = tid;
        const float* Lb = L + (size_t)b * TT;
        const float* Rb = R + (size_t)b * TT;
        const float* pL = pLR;
        const float* pR = pLR + TT;
        float s = Lb[3 * n] + Lb[3 * n + 1] + Rb[3 * n] + Rb[3 * n + 1] + Rb[3 * n + 2]
                + pL[3 * n] + pL[3 * n + 1] + pR[3 * n] + pR[3 * n + 1] + pR[3 * n + 2];
        if (n > 0) s += Lb[3 * n - 1] + pL[3 * n - 1];
        sy[n] = s * (1.0f / (3.0f * (float)CC));
    }
    __syncthreads();
    if (tid < NBB) {
        float s = 0.0f;
        for (int j = 0; j < NBB; ++j) s += fc1[tid * NBB + j] * sy[j];
        sz[tid] = fmaxf(s, 0.0f);
    }
    __syncthreads();
    if (tid < NBB) {
        float s = 0.0f;
        for (int j = 0; j < NBB; ++j) s += fc2[tid * NBB + j] * sz[j];
        swv[tid] = 1.0f / (1.0f + expf(-s));
    }
    __syncthreads();
    // wave-parallel top-6 (wave 0); tie-break: lowest index (matches top_k)
    if (w == 0) {
        float va = (lane < NBB) ? swv[lane] : -1e30f;
        float vb = (lane + 64 < NBB) ? swv[lane + 64] : -1e30f;
        const int ia = lane, ib = lane + 64;
        for (int kk = 0; kk < KK; ++kk) {
            float v = va; int idx = ia;
            if (vb > v) { v = vb; idx = ib; }
#pragma unroll
            for (int m = 1; m < 64; m <<= 1) {
                const float ov = __shfl_xor(v, m);
                const int oi = __shfl_xor(idx, m);
                if (ov > v || (ov == v && oi < idx)) { v = ov; idx = oi; }
            }
            if (lane == 0) sidx[kk] = idx;
            if (ia == idx) va = -1e30f;
            if (ib == idx) vb = -1e30f;
        }
    }
    __syncthreads();

    // gather -> st (LDS) + t (global f32)
    for (int i = tid; i < KK * 136; i += 128) {
        const int k = i / 136;
        const int c4 = i - k * 136;
        const int n = sidx[k];
        const int shift = (c4 < 68) ? -1 : 0;
        float ax = 0.f, ay = 0.f, az = 0.f, aw = 0.f;
#pragma unroll
        for (int i2 = 0; i2 < 3; ++i2) {
            const int ttr = 3 * n + i2 + shift;
            if (ttr >= 0) {
                const float4 xv = x4[((size_t)b * TT + ttr) * 136 + c4];
                const float4 pv = p4[(size_t)ttr * 136 + c4];
                ax += xv.x + pv.x; ay += xv.y + pv.y; az += xv.z + pv.z; aw += xv.w + pv.w;
            }
        }
        const float inv3 = 1.0f / 3.0f;
        const float4 a = make_float4(ax * inv3, ay * inv3, az * inv3, aw * inv3);
        *(float4*)&st[k][c4 * 4] = a;
        ((float4*)t)[((size_t)b * KK + k) * 136 + c4] = a;
    }
    __syncthreads();

    // ln1 (layer 0): wave w handles rows w and w+2? (2 waves, 6 rows => loop)
    for (int k = w; k < KK; k += 2) {
        float s = 0.0f, s2 = 0.0f;
        for (int c = lane; c < CC; c += 64) { const float v = st[k][c]; s += v; s2 += v * v; }
#pragma unroll
        for (int off = 32; off; off >>= 1) {
            s += __shfl_xor(s, off);
            s2 += __shfl_xor(s2, off);
        }
        const float m = s / (float)CC;
        const float inv = rsqrtf(s2 / (float)CC - m * m + EPSF);
        for (int c4 = lane; c4 < 136; c4 += 64) {
            const float4 v = *(const float4*)&st[k][c4 * 4];
            const float4 gv = ((const float4*)ln1g)[c4];
            const float4 bv = ((const float4*)ln1b)[c4];
            ushort4 o;
            o.x = f2bu((v.x - m) * inv * gv.x + bv.x);
            o.y = f2bu((v.y - m) * inv * gv.y + bv.y);
            o.z = f2bu((v.z - m) * inv * gv.z + bv.z);
            o.w = f2bu((v.w - m) * inv * gv.w + bv.w);
            ((ushort4*)hb)[((size_t)b * KK + k) * 136 + c4] = o;
        }
    }
}

// ---------------------------------------------------------------------------
// LayerNorm over last dim (544): 4 rows/block, wave per row, no syncthreads
// ---------------------------------------------------------------------------
__global__ __launch_bounds__(256) void ln_bf16_kernel(
    const float* __restrict__ X,   // M x 544
    const float* __restrict__ g,   // 544
    const float* __restrict__ bta, // 544
    unsigned short* __restrict__ Y)
{
    const int row = blockIdx.x * 4 + (threadIdx.x >> 6);
    const int lane = threadIdx.x & 63;
    const float4* xr4 = (const float4*)(X + (size_t)row * CC);
    const float4 v0 = xr4[lane];
    const float4 v1 = xr4[lane + 64];
    float4 v2 = make_float4(0.f, 0.f, 0.f, 0.f);
    if (lane < 8) v2 = xr4[lane + 128];
    float s = (v0.x + v0.y + v0.z + v0.w) + (v1.x + v1.y + v1.z + v1.w)
            + (v2.x + v2.y + v2.z + v2.w);
    float s2 = (v0.x * v0.x + v0.y * v0.y + v0.z * v0.z + v0.w * v0.w)
             + (v1.x * v1.x + v1.y * v1.y + v1.z * v1.z + v1.w * v1.w)
             + (v2.x * v2.x + v2.y * v2.y + v2.z * v2.z + v2.w * v2.w);
#pragma unroll
    for (int off = 32; off; off >>= 1) {
        s += __shfl_xor(s, off);
        s2 += __shfl_xor(s2, off);
    }
    const float m = s / (float)CC;
    const float inv = rsqrtf(s2 / (float)CC - m * m + EPSF);
    ushort4* yr = (ushort4*)(Y + (size_t)row * CC);
    {
        const float4 gv = ((const float4*)g)[lane];
        const float4 bv = ((const float4*)bta)[lane];
        ushort4 o;
        o.x = f2bu((v0.x - m) * inv * gv.x + bv.x);
        o.y = f2bu((v0.y - m) * inv * gv.y + bv.y);
        o.z = f2bu((v0.z - m) * inv * gv.z + bv.z);
        o.w = f2bu((v0.w - m) * inv * gv.w + bv.w);
        yr[lane] = o;
    }
    {
        const float4 gv = ((const float4*)g)[lane + 64];
        const float4 bv = ((const float4*)bta)[lane + 64];
        ushort4 o;
        o.x = f2bu((v1.x - m) * inv * gv.x + bv.x);
        o.y = f2bu((v1.y - m) * inv * gv.y + bv.y);
        o.z = f2bu((v1.z - m) * inv * gv.z + bv.z);
        o.w = f2bu((v1.w - m) * inv * gv.w + bv.w);
        yr[lane + 64] = o;
    }
    if (lane < 8) {
        const float4 gv = ((const float4*)g)[lane + 128];
        const float4 bv = ((const float4*)bta)[lane + 128];
        ushort4 o;
        o.x = f2bu((v2.x - m) * inv * gv.x + bv.x);
        o.y = f2bu((v2.y - m) * inv * gv.y + bv.y);
        o.z = f2bu((v2.z - m) * inv * gv.z + bv.z);
        o.w = f2bu((v2.w - m) * inv * gv.w + bv.w);
        yr[lane + 128] = o;
    }
}

// ---------------------------------------------------------------------------
// bf16 MFMA GEMM: Y[M,N] = act(Xbf[M,K] @ Wbf[N,K]^T + bias[N]) (+R) (f32/bf16 out)
// 128x128 tile, BK=32, 256 threads = 4 waves (2x2), wave tile 64x64
// ---------------------------------------------------------------------------
template <int ACT, int RES, int OBF>
__global__ __launch_bounds__(256) void gemm_mfma_kernel(
    const unsigned short* __restrict__ X,   // bf16 M x K
    const unsigned short* __restrict__ W,   // bf16 N x K
    const float* __restrict__ bias,         // N
    const float* __restrict__ R,            // M x N (f32) or null
    void* __restrict__ Y,                   // f32 or bf16
    int M, int N, int Kd)
{
    const int bm = blockIdx.y * 128;
    const int bn = blockIdx.x * 128;
    const int tid = threadIdx.x;
    const int K8 = Kd >> 3;    // uint4 per row

    __shared__ __align__(16) short As[128][40];
    __shared__ __align__(16) short Bs[128][40];

    const int r0 = tid >> 2;           // rows 0..63
    const int c0 = tid & 3;            // chunk 0..3
    const int r1 = r0 + 64;            // rows 64..127

    const uint4* Xu = (const uint4*)X;
    const uint4* Wu = (const uint4*)W;

    const int wid = tid >> 6;
    const int lane = tid & 63;
    const int wm = (wid >> 1) * 64;
    const int wn = (wid & 1) * 64;
    const int l16 = lane & 15;
    const int l4 = lane >> 4;          // 0..3
    const int koff = l4 * 8;

    f32x4 acc[4][4] = {};

    const int wr0 = min(bn + r0, N - 1);
    const int wr1 = min(bn + r1, N - 1);

    uint4 a0 = Xu[(size_t)(bm + r0) * K8 + c0];
    uint4 a1 = Xu[(size_t)(bm + r1) * K8 + c0];
    uint4 b0 = Wu[(size_t)wr0 * K8 + c0];
    uint4 b1 = Wu[(size_t)wr1 * K8 + c0];

    const int nk = Kd >> 5;
    for (int kt = 0; kt < nk; ++kt) {
        __syncthreads();
        *(uint4*)&As[r0][c0 * 8] = a0;
        *(uint4*)&As[r1][c0 * 8] = a1;
        *(uint4*)&Bs[r0][c0 * 8] = b0;
        *(uint4*)&Bs[r1][c0 * 8] = b1;
        __syncthreads();

        const bool more = (kt + 1 < nk);
        uint4 na0, na1, nb0, nb1;
        if (more) {
            const int kc = (kt + 1) * 4 + c0;
            na0 = Xu[(size_t)(bm + r0) * K8 + kc];
            na1 = Xu[(size_t)(bm + r1) * K8 + kc];
            nb0 = Wu[(size_t)wr0 * K8 + kc];
            nb1 = Wu[(size_t)wr1 * K8 + kc];
        }

        bf16x8 af[4], bf[4];
#pragma unroll
        for (int mf = 0; mf < 4; ++mf) af[mf] = *(const bf16x8*)&As[wm + mf * 16 + l16][koff];
#pragma unroll
        for (int nf = 0; nf < 4; ++nf) bf[nf] = *(const bf16x8*)&Bs[wn + nf * 16 + l16][koff];
#pragma unroll
        for (int mf = 0; mf < 4; ++mf)
#pragma unroll
            for (int nf = 0; nf < 4; ++nf)
                acc[mf][nf] = __builtin_amdgcn_mfma_f32_16x16x32_bf16(af[mf], bf[nf], acc[mf][nf], 0, 0, 0);

        if (more) { a0 = na0; a1 = na1; b0 = nb0; b1 = nb1; }
    }

    // epilogue
#pragma unroll
    for (int nf = 0; nf < 4; ++nf) {
        const int col = bn + wn + nf * 16 + l16;
        if (col < N) {
            const float bs = bias[col];
#pragma unroll
            for (int mf = 0; mf < 4; ++mf) {
#pragma unroll
                for (int j = 0; j < 4; ++j) {
                    const int row = bm + wm + mf * 16 + l4 * 4 + j;
                    float v = acc[mf][nf][j] + bs;
                    if (ACT == 1) v = 0.5f * v * (1.0f + erff(v * 0.70710678118654752f));
                    if (RES) v += R[(size_t)row * N + col];
                    if (OBF) ((__hip_bfloat16*)Y)[(size_t)row * N + col] = f2b(v);
                    else     ((float*)Y)[(size_t)row * N + col] = v;
                }
            }
        }
    }
}

// ---------------------------------------------------------------------------
// Attention: per block b; 8 waves = 8 heads; 6 tokens, head dim 68
// input qkv in bf16, staged to f32 LDS; out bf16
// ---------------------------------------------------------------------------
__global__ __launch_bounds__(512) void attn_kernel(
    const unsigned short* __restrict__ qkv,  // B*6*1632 bf16
    __hip_bfloat16* __restrict__ o)          // B*6*544 bf16
{
    const int b = blockIdx.x;
    __shared__ __align__(16) float sq[KK * 3 * CC];
    __shared__ float sp[HH][40];
    const int tid = threadIdx.x;

    const uint4* src4 = (const uint4*)(qkv + (size_t)b * KK * 3 * CC);  // 1224 uint4
    for (int i = tid; i < (KK * 3 * CC) / 8; i += 512) {
        const uint4 u = src4[i];
        float4 f0, f1;
        f0.x = b2f_lo(u.x); f0.y = b2f_hi(u.x);
        f0.z = b2f_lo(u.y); f0.w = b2f_hi(u.y);
        f1.x = b2f_lo(u.z); f1.y = b2f_hi(u.z);
        f1.z = b2f_lo(u.w); f1.w = b2f_hi(u.w);
        ((float4*)sq)[2 * i] = f0;
        ((float4*)sq)[2 * i + 1] = f1;
    }
    __syncthreads();

    const int h = tid >> 6;
    const int lane = tid & 63;
    const float scl = rsqrtf((float)HD);

    if (lane < KK * KK) {
        const int n = lane / KK, m = lane - (lane / KK) * KK;
        const float* qp = &sq[n * (3 * CC) + 0 * CC + h * HD];
        const float* kp = &sq[m * (3 * CC) + 1 * CC + h * HD];
        float s = 0.0f;
#pragma unroll 4
        for (int d = 0; d < HD; ++d) s += qp[d] * kp[d];
        sp[h][lane] = s * scl;
    }
    __syncthreads();
    if (lane < KK) {
        const int n = lane;
        float mx = -1e30f;
#pragma unroll
        for (int m = 0; m < KK; ++m) mx = fmaxf(mx, sp[h][n * KK + m]);
        float e[KK];
        float sum = 0.0f;
#pragma unroll
        for (int m = 0; m < KK; ++m) { e[m] = expf(sp[h][n * KK + m] - mx); sum += e[m]; }
        const float inv = 1.0f / sum;
#pragma unroll
        for (int m = 0; m < KK; ++m) sp[h][n * KK + m] = e[m] * inv;
    }
    __syncthreads();
    for (int i = tid; i < KK * CC; i += 512) {
        const int n = i / CC;
        const int cd = i - n * CC;
        const int hh = cd / HD;
        const int d = cd - hh * HD;
        float acc = 0.0f;
#pragma unroll
        for (int m = 0; m < KK; ++m)
            acc += sp[hh][n * KK + m] * sq[m * (3 * CC) + 2 * CC + hh * HD + d];
        o[(size_t)b * KK * CC + i] = f2b(acc);
    }
}

// ---------------------------------------------------------------------------
// Final: LN(t) with lnf, then out[b,c] = sum_k tln[b,k,c]*wm2_w[k] + wm2_b
// ---------------------------------------------------------------------------
__global__ __launch_bounds__(256) void final_kernel(
    const float* __restrict__ t,     // B*6*544
    const float* __restrict__ g,
    const float* __restrict__ bta,
    const float* __restrict__ wm2w,  // 6
    const float* __restrict__ wm2b,  // 1
    float* __restrict__ out)         // B*544
{
    const int b = blockIdx.x;
    const int tid = threadIdx.x;
    __shared__ float st[KK][CC];
    __shared__ float sm[KK], si[KK];
    const float* tb = t + (size_t)b * KK * CC;
    for (int i = tid; i < KK * CC; i += 256) st[i / CC][i % CC] = tb[i];
    __syncthreads();
    const int wid = tid >> 6, lane = tid & 63;
    for (int r = wid; r < KK; r += 4) {
        float s = 0.0f, s2 = 0.0f;
        for (int c = lane; c < CC; c += 64) { const float v = st[r][c]; s += v; s2 += v * v; }
#pragma unroll
        for (int off = 32; off; off >>= 1) { s += __shfl_xor(s, off); s2 += __shfl_xor(s2, off); }
        if (lane == 0) {
            const float m = s / (float)CC;
            sm[r] = m;
            si[r] = rsqrtf(s2 / (float)CC - m * m + EPSF);
        }
    }
    __syncthreads();
    const float w0 = wm2w[0], w1 = wm2w[1], w2 = wm2w[2], w3 = wm2w[3], w4 = wm2w[4], w5 = wm2w[5];
    const float wb = wm2b[0];
    for (int c = tid; c < CC; c += 256) {
        const float gg = g[c], bb = bta[c];
        float acc = wb;
        acc += w0 * ((st[0][c] - sm[0]) * si[0] * gg + bb);
        acc += w1 * ((st[1][c] - sm[1]) * si[1] * gg + bb);
        acc += w2 * ((st[2][c] - sm[2]) * si[2] * gg + bb);
        acc += w3 * ((st[3][c] - sm[3]) * si[3] * gg + bb);
        acc += w4 * ((st[4][c] - sm[4]) * si[4] * gg + bb);
        acc += w5 * ((st[5][c] - sm[5]) * si[5] * gg + bb);
        out[(size_t)b * CC + c] = acc;
    }
}

// ---------------------------------------------------------------------------
extern "C" void kernel_launch(void* const* d_in, const int* in_sizes, int n_in,
                              void* d_out, int out_size, void* d_ws, size_t ws_size,
                              hipStream_t stream)
{
    const float* x      = (const float*)d_in[0];
    const float* pos    = (const float*)d_in[1];
    const float* fc1_w  = (const float*)d_in[2];
    const float* fc2_w  = (const float*)d_in[3];
    const float* ln1_g  = (const float*)d_in[4];
    const float* ln1_b  = (const float*)d_in[5];
    const float* qkv_w  = (const float*)d_in[6];
    const float* qkv_b  = (const float*)d_in[7];
    const float* proj_w = (const float*)d_in[8];
    const float* proj_b = (const float*)d_in[9];
    const float* ln2_g  = (const float*)d_in[10];
    const float* ln2_b  = (const float*)d_in[11];
    const float* mfc1_w = (const float*)d_in[12];
    const float* mfc1_b = (const float*)d_in[13];
    const float* mfc2_w = (const float*)d_in[14];
    const float* mfc2_b = (const float*)d_in[15];
    const float* lnf_g  = (const float*)d_in[16];
    const float* lnf_b  = (const float*)d_in[17];
    const float* wm2_w  = (const float*)d_in[18];
    const float* wm2_b  = (const float*)d_in[19];

    float* ws = (float*)d_ws;
    float* L    = ws;                              // 124416
    float* R    = L + 124416;                      // 124416
    float* pLR  = R + 124416;                      // 486
    float* t    = pLR + 512;                       // 3072*544 f32
    unsigned short* qkvb = (unsigned short*)(t + (size_t)MTOK * CC); // 3072*1632 bf16
    unsigned short* hb  = qkvb + (size_t)MTOK * 3 * CC;              // 3072*544 bf16
    unsigned short* ob  = hb + (size_t)MTOK * CC;                    // 3072*544 bf16
    unsigned short* gb  = ob + (size_t)MTOK * CC;                    // 3072*1088 bf16
    unsigned short* wbf = gb + (size_t)MTOK * HID;                   // 4,734,976 bf16

    unsigned short* wqkv = wbf;                         // 2 x (1632*544)
    unsigned short* wprj = wbf + 1775616;               // 2 x (544*544)
    unsigned short* wf1  = wbf + 2367488;               // 2 x (1088*544)
    unsigned short* wf2  = wbf + 3551232;               // 2 x (544*1088)

    // pure-BW pass: x row half-sums || pos row half-sums || weight conversion
    bw_kernel<<<BW_GRID, 256, 0, stream>>>(
        x, pos, qkv_w, proj_w, mfc1_w, mfc2_w, wbf, L, R, pLR);

    // selection + gather + ln1 (layer 0)
    select_kernel<<<BB, 128, 0, stream>>>(
        L, R, pLR, fc1_w, fc2_w, x, pos, ln1_g, ln1_b, t, hb);

    for (int i = 0; i < DEPTH; ++i) {
        if (i > 0) {
            ln_bf16_kernel<<<MTOK / 4, 256, 0, stream>>>(t, ln1_g + i * CC, ln1_b + i * CC, hb);
        }
        gemm_mfma_kernel<0, 0, 1><<<dim3(13, 24), 256, 0, stream>>>(
            hb, wqkv + (size_t)i * 1632 * 544, qkv_b + (size_t)i * 3 * CC,
            nullptr, qkvb, MTOK, 3 * CC, CC);
        attn_kernel<<<BB, 512, 0, stream>>>(qkvb, (__hip_bfloat16*)ob);
        gemm_mfma_kernel<0, 1, 0><<<dim3(5, 24), 256, 0, stream>>>(
            ob, wprj + (size_t)i * 544 * 544, proj_b + (size_t)i * CC,
            t, t, MTOK, CC, CC);
        ln_bf16_kernel<<<MTOK / 4, 256, 0, stream>>>(t, ln2_g + i * CC, ln2_b + i * CC, hb);
        gemm_mfma_kernel<1, 0, 1><<<dim3(9, 24), 256, 0, stream>>>(
            hb, wf1 + (size_t)i * HID * 544, mfc1_b + (size_t)i * HID,
            nullptr, gb, MTOK, HID, CC);
        gemm_mfma_kernel<0, 1, 0><<<dim3(5, 24), 256, 0, stream>>>(
            gb, wf2 + (size_t)i * 544 * HID, mfc2_b + (size_t)i * CC,
            t, t, MTOK, CC, HID);
    }

    final_kernel<<<BB, 256, 0, stream>>>(t, lnf_g, lnf_b, wm2_w, wm2_b, (float*)d_out);
}